// Round 8
// baseline (345.840 us; speedup 1.0000x reference)
//
#include <hip/hip_runtime.h>

#define NN 100000
#define NE 1200000
#define HD 64
#define NG 512
#define BN_EPS 1e-5f
#define CAP 48          // max degree; P(Poisson(12) >= 48) ~ 6e-17 per node

__device__ __forceinline__ float bf_lo(unsigned v) { return __uint_as_float(v << 16); }
__device__ __forceinline__ float bf_hi(unsigned v) { return __uint_as_float(v & 0xffff0000u); }
__device__ __forceinline__ unsigned bpack(float a, float b) {
    unsigned ua = __float_as_uint(a), ub = __float_as_uint(b);
    ua = (ua + 0x7fffu + ((ua >> 16) & 1u)) >> 16;
    ub = (ub + 0x7fffu + ((ub >> 16) & 1u)) >> 16;
    return ua | (ub << 16);
}

__global__ __launch_bounds__(256) void k_zero_int(int* __restrict__ a, int n) {
    int i = blockIdx.x * 256 + threadIdx.x;
    if (i < n) a[i] = 0;
}

// x fp32 -> bf16 (packed pairs), 8 floats/thread
__global__ __launch_bounds__(256) void k_cvt(const float4* __restrict__ xf, uint4* __restrict__ xb, int n4) {
    int i = blockIdx.x * 256 + threadIdx.x;
    if (i < n4) {
        float4 f0 = xf[2 * i], f1 = xf[2 * i + 1];
        uint4 o;
        o.x = bpack(f0.x, f0.y); o.y = bpack(f0.z, f0.w);
        o.z = bpack(f1.x, f1.y); o.w = bpack(f1.z, f1.w);
        xb[i] = o;
    }
}

// direct bucket CSR build; csrB stores are NON-TEMPORAL: stream past the
// per-XCD L2s (whose write-allocate/evict churn cost 60B/edge) and merge at
// the memory-side Infinity Cache instead.
__global__ __launch_bounds__(256) void k_fillb(const int* __restrict__ src, const int* __restrict__ dst,
                                               int* __restrict__ deg, int* __restrict__ csrB) {
    int e = blockIdx.x * 256 + threadIdx.x;
    if (e < NE) {
        int d = dst[e];
        int r = atomicAdd(&deg[d], 1);
        if (r < CAP) __builtin_nontemporal_store(src[e], &csrB[(size_t)d * CAP + r]);
    }
}

// gather (bf16 input rows): u[i] = x[i] + sum_nbr x[s]; 8 lanes/node, uint4 (8 bf16) each
__global__ __launch_bounds__(256) void k_agg8(const uint4* __restrict__ xb, float* __restrict__ u,
                                              const int* __restrict__ deg, const int* __restrict__ csrB) {
    int gid = blockIdx.x * 256 + threadIdx.x;
    int node = gid >> 3;
    if (node >= NN) return;
    int c = gid & 7;
    uint4 sv = xb[(size_t)node * 8 + c];
    float a0 = bf_lo(sv.x), a1 = bf_hi(sv.x), a2 = bf_lo(sv.y), a3 = bf_hi(sv.y);
    float a4 = bf_lo(sv.z), a5 = bf_hi(sv.z), a6 = bf_lo(sv.w), a7 = bf_hi(sv.w);
    int cnt = deg[node]; if (cnt > CAP) cnt = CAP;
    const int* row = csrB + (size_t)node * CAP;
    int e = 0;
    for (; e + 4 <= cnt; e += 4) {
        int s0 = row[e], s1 = row[e + 1], s2 = row[e + 2], s3 = row[e + 3];
        uint4 v0 = xb[(size_t)s0 * 8 + c];
        uint4 v1 = xb[(size_t)s1 * 8 + c];
        uint4 v2 = xb[(size_t)s2 * 8 + c];
        uint4 v3 = xb[(size_t)s3 * 8 + c];
        a0 += (bf_lo(v0.x) + bf_lo(v1.x)) + (bf_lo(v2.x) + bf_lo(v3.x));
        a1 += (bf_hi(v0.x) + bf_hi(v1.x)) + (bf_hi(v2.x) + bf_hi(v3.x));
        a2 += (bf_lo(v0.y) + bf_lo(v1.y)) + (bf_lo(v2.y) + bf_lo(v3.y));
        a3 += (bf_hi(v0.y) + bf_hi(v1.y)) + (bf_hi(v2.y) + bf_hi(v3.y));
        a4 += (bf_lo(v0.z) + bf_lo(v1.z)) + (bf_lo(v2.z) + bf_lo(v3.z));
        a5 += (bf_hi(v0.z) + bf_hi(v1.z)) + (bf_hi(v2.z) + bf_hi(v3.z));
        a6 += (bf_lo(v0.w) + bf_lo(v1.w)) + (bf_lo(v2.w) + bf_lo(v3.w));
        a7 += (bf_hi(v0.w) + bf_hi(v1.w)) + (bf_hi(v2.w) + bf_hi(v3.w));
    }
    for (; e < cnt; ++e) {
        uint4 v = xb[(size_t)row[e] * 8 + c];
        a0 += bf_lo(v.x); a1 += bf_hi(v.x); a2 += bf_lo(v.y); a3 += bf_hi(v.y);
        a4 += bf_lo(v.z); a5 += bf_hi(v.z); a6 += bf_lo(v.w); a7 += bf_hi(v.w);
    }
    float4* u4 = reinterpret_cast<float4*>(u);
    u4[(size_t)node * 16 + 2 * c]     = make_float4(a0, a1, a2, a3);
    u4[(size_t)node * 16 + 2 * c + 1] = make_float4(a4, a5, a6, a7);
}

// MLP + pool: h_bf16 = relu( relu(BN(u @ W1 + b1)) @ W2 + b2 ); pool into p (atomic per segment)
__global__ __launch_bounds__(256) void k_mlp(const float* __restrict__ u, uint2* __restrict__ hout,
                                             const int* __restrict__ batch, float* __restrict__ p, int layer,
                                             const float* __restrict__ W1, const float* __restrict__ b1,
                                             const float* __restrict__ gamma, const float* __restrict__ beta,
                                             const float* __restrict__ rm, const float* __restrict__ rv,
                                             const float* __restrict__ W2, const float* __restrict__ b2) {
    __shared__ __align__(16) float sW1[64][68];
    __shared__ __align__(16) float sW2[64][68];
    __shared__ __align__(16) float sUT[64][68];   // input^T, then intermediate^T, then output [row][col]
    __shared__ float ssc[64], sb1[64], sb2[64];
    __shared__ int sbatch[64];
    const int t = threadIdx.x;
    const int base = blockIdx.x * 64;

    if (t < 64) {
        float sc = gamma[t] * rsqrtf(rv[t] + BN_EPS);
        ssc[t] = sc;
        sb1[t] = (b1[t] - rm[t]) * sc + beta[t];
        sb2[t] = b2[t];
        int row = base + t;
        sbatch[t] = (row < NN) ? batch[row] : -1;
    }
    __syncthreads();
#pragma unroll
    for (int s = 0; s < 16; ++s) {
        int i = t + 256 * s;
        int k = i >> 6, j = i & 63;
        sW1[k][j] = W1[i] * ssc[j];
        sW2[k][j] = W2[i];
    }
    const float4* u4 = reinterpret_cast<const float4*>(u);
#pragma unroll
    for (int s = 0; s < 4; ++s) {
        int i4 = t + 256 * s;
        int r = i4 >> 4, c = i4 & 15;
        int row = base + r;
        float4 v = (row < NN) ? u4[(size_t)row * 16 + c] : make_float4(0.f, 0.f, 0.f, 0.f);
        sUT[c * 4 + 0][r] = v.x; sUT[c * 4 + 1][r] = v.y;
        sUT[c * 4 + 2][r] = v.z; sUT[c * 4 + 3][r] = v.w;
    }
    __syncthreads();

    const int rg4 = (t >> 4) * 4;
    const int cg4 = (t & 15) * 4;
    float acc[4][4];
#pragma unroll
    for (int m = 0; m < 4; ++m)
#pragma unroll
        for (int cc = 0; cc < 4; ++cc) acc[m][cc] = sb1[cg4 + cc];

#pragma unroll 8
    for (int k = 0; k < 64; ++k) {
        float4 a = *reinterpret_cast<const float4*>(&sUT[k][rg4]);
        float4 b = *reinterpret_cast<const float4*>(&sW1[k][cg4]);
        float av[4] = {a.x, a.y, a.z, a.w};
        float bv[4] = {b.x, b.y, b.z, b.w};
#pragma unroll
        for (int m = 0; m < 4; ++m)
#pragma unroll
            for (int cc = 0; cc < 4; ++cc) acc[m][cc] = fmaf(av[m], bv[cc], acc[m][cc]);
    }
    __syncthreads();
#pragma unroll
    for (int cc = 0; cc < 4; ++cc)
#pragma unroll
        for (int m = 0; m < 4; ++m)
            sUT[cg4 + cc][rg4 + m] = fmaxf(acc[m][cc], 0.f);
    __syncthreads();

#pragma unroll
    for (int m = 0; m < 4; ++m)
#pragma unroll
        for (int cc = 0; cc < 4; ++cc) acc[m][cc] = sb2[cg4 + cc];

#pragma unroll 8
    for (int k = 0; k < 64; ++k) {
        float4 a = *reinterpret_cast<const float4*>(&sUT[k][rg4]);
        float4 b = *reinterpret_cast<const float4*>(&sW2[k][cg4]);
        float av[4] = {a.x, a.y, a.z, a.w};
        float bv[4] = {b.x, b.y, b.z, b.w};
#pragma unroll
        for (int m = 0; m < 4; ++m)
#pragma unroll
            for (int cc = 0; cc < 4; ++cc) acc[m][cc] = fmaf(av[m], bv[cc], acc[m][cc]);
    }
    __syncthreads();   // sUT reads done; reuse as [row][col] output stage
#pragma unroll
    for (int m = 0; m < 4; ++m) {
        int row = base + rg4 + m;
        float o0 = fmaxf(acc[m][0], 0.f), o1 = fmaxf(acc[m][1], 0.f);
        float o2 = fmaxf(acc[m][2], 0.f), o3 = fmaxf(acc[m][3], 0.f);
        if (row < NN) {
            uint2 hv; hv.x = bpack(o0, o1); hv.y = bpack(o2, o3);
            hout[(size_t)row * 16 + (t & 15)] = hv;
        }
        sUT[rg4 + m][cg4 + 0] = o0; sUT[rg4 + m][cg4 + 1] = o1;
        sUT[rg4 + m][cg4 + 2] = o2; sUT[rg4 + m][cg4 + 3] = o3;
    }
    __syncthreads();

    if (t < 64) {
        const int j = t;
        float pa = 0.f;
        int gprev = -1;
        for (int r = 0; r < 64; ++r) {
            int row = base + r;
            if (row >= NN) break;
            int g = sbatch[r];
            if (g != gprev) {
                if (gprev >= 0) atomicAdd(&p[gprev * 192 + layer * 64 + j], pa);
                pa = 0.f; gprev = g;
            }
            pa += sUT[r][j];
        }
        if (gprev >= 0) atomicAdd(&p[gprev * 192 + layer * 64 + j], pa);
    }
}

__global__ __launch_bounds__(192) void k_final(const float* __restrict__ p,
                                               const float* __restrict__ W1, const float* __restrict__ b1,
                                               const float* __restrict__ W2, const float* __restrict__ b2,
                                               float* __restrict__ out) {
    int g = blockIdx.x, t = threadIdx.x;
    __shared__ float hg[192];
    __shared__ float y1[192];
    __shared__ float y2[2];
    hg[t] = p[g * 192 + t];
    __syncthreads();
    float acc = b1[t];
    for (int k = 0; k < 192; ++k) acc = fmaf(hg[k], W1[k * 192 + t], acc);
    y1[t] = fmaxf(acc, 0.f);
    __syncthreads();
    if (t < 2) {
        float a = b2[t];
        for (int k = 0; k < 192; ++k) a = fmaf(y1[k], W2[k * 2 + t], a);
        y2[t] = a;
    }
    __syncthreads();
    if (t < 2) {
        float m = fmaxf(y2[0], y2[1]);
        float s = expf(y2[0] - m) + expf(y2[1] - m);
        out[g * 2 + t] = y2[t];
        out[NG * 2 + g * 2 + t] = expf(y2[t] - m) / s;
    }
}

extern "C" void kernel_launch(void* const* d_in, const int* in_sizes, int n_in,
                              void* d_out, int out_size, void* d_ws, size_t ws_size,
                              hipStream_t stream) {
    const float* x    = (const float*)d_in[0];
    const int* ei     = (const int*)d_in[1];
    const int* batch  = (const int*)d_in[2];
    const int* src    = ei;
    const int* dst    = ei + NE;
    const float* lin1_W = (const float*)d_in[27];
    const float* lin1_b = (const float*)d_in[28];
    const float* lin2_W = (const float*)d_in[29];
    const float* lin2_b = (const float*)d_in[30];

    // ws layout (total = 71,193,216 B, bound proven available in rounds 3-7):
    char* w = (char*)d_ws;
    int*   deg  = (int*)w;                                   //   400,000
    float* p    = (float*)(w + 400000);                      //   393,216
    float* u    = (float*)(w + 793216);                      // 25,600,000 fp32 [NN][64]
    char*  xbhB = w + 26393216;                              // 12,800,000 bf16: x_bf, later hB
    char*  hA   = w + 39193216;                              // 12,800,000 bf16
    int*   csrB = (int*)(w + 51993216);                      // 19,200,000 [NN][CAP]

    // zero deg + p (contiguous)
    k_zero_int<<<(198304 + 255) / 256, 256, 0, stream>>>(deg, 198304);
    // x -> bf16
    k_cvt<<<(NN * 8 + 255) / 256, 256, 0, stream>>>((const float4*)x, (uint4*)xbhB, NN * 8);
    // direct CSR build with non-temporal payload stores
    k_fillb<<<(NE + 255) / 256, 256, 0, stream>>>(src, dst, deg, csrB);

    const uint4* gin[3]  = { (const uint4*)xbhB, (const uint4*)hA, (const uint4*)xbhB };
    uint2*       gout[3] = { (uint2*)hA,         (uint2*)xbhB,     (uint2*)hA };
    for (int l = 0; l < 3; ++l) {
        const float* W1 = (const float*)d_in[3 + 8 * l + 0];
        const float* b1 = (const float*)d_in[3 + 8 * l + 1];
        const float* ga = (const float*)d_in[3 + 8 * l + 2];
        const float* be = (const float*)d_in[3 + 8 * l + 3];
        const float* rm = (const float*)d_in[3 + 8 * l + 4];
        const float* rv = (const float*)d_in[3 + 8 * l + 5];
        const float* W2 = (const float*)d_in[3 + 8 * l + 6];
        const float* b2 = (const float*)d_in[3 + 8 * l + 7];

        k_agg8<<<(NN * 8 + 255) / 256, 256, 0, stream>>>(gin[l], u, deg, csrB);
        k_mlp<<<(NN + 63) / 64, 256, 0, stream>>>(u, gout[l], batch, p, l,
                                                  W1, b1, ga, be, rm, rv, W2, b2);
    }
    k_final<<<NG, 192, 0, stream>>>(p, lin1_W, lin1_b, lin2_W, lin2_b, (float*)d_out);
}

// Round 9
// 310.696 us; speedup vs baseline: 1.1131x; 1.1131x over previous
//
#include <hip/hip_runtime.h>

#define NN 100000
#define NE 1200000
#define HD 64
#define NG 512
#define BN_EPS 1e-5f
#define CAP 48          // max degree; P(Poisson(12) >= 48) ~ 6e-17 per node
#define SLICE 12500     // NN/8 dst-nodes per XCD shard
#define FBLK 128        // blocks per shard (grid = 8*FBLK)

__device__ __forceinline__ float bf_lo(unsigned v) { return __uint_as_float(v << 16); }
__device__ __forceinline__ float bf_hi(unsigned v) { return __uint_as_float(v & 0xffff0000u); }
__device__ __forceinline__ unsigned bpack(float a, float b) {
    unsigned ua = __float_as_uint(a), ub = __float_as_uint(b);
    ua = (ua + 0x7fffu + ((ua >> 16) & 1u)) >> 16;
    ub = (ub + 0x7fffu + ((ub >> 16) & 1u)) >> 16;
    return ua | (ub << 16);
}

__global__ __launch_bounds__(256) void k_zero_int(int* __restrict__ a, int n) {
    int i = blockIdx.x * 256 + threadIdx.x;
    if (i < n) a[i] = 0;
}

// x fp32 -> bf16 (packed pairs), 8 floats/thread
__global__ __launch_bounds__(256) void k_cvt(const float4* __restrict__ xf, uint4* __restrict__ xb, int n4) {
    int i = blockIdx.x * 256 + threadIdx.x;
    if (i < n4) {
        float4 f0 = xf[2 * i], f1 = xf[2 * i + 1];
        uint4 o;
        o.x = bpack(f0.x, f0.y); o.y = bpack(f0.z, f0.w);
        o.z = bpack(f1.x, f1.y); o.w = bpack(f1.z, f1.w);
        xb[i] = o;
    }
}

// XCD-sharded CSR build: group g (= blockIdx&7, round-robin -> one XCD) scans
// the whole edge list and keeps only dst in its 12500-node slice. Each XCD's
// L2 then owns a 2.4MB csrB slice + 50KB of counters: a node's ~12 writes
// merge in L2 before ONE writeback (vs one 64B writeback per edge before).
__global__ __launch_bounds__(256) void k_fills(const int* __restrict__ src, const int* __restrict__ dst,
                                               int* __restrict__ deg, int* __restrict__ csrB) {
    const int g = blockIdx.x & 7;
    const int lo = g * SLICE, hi = lo + SLICE;
    const int r = (blockIdx.x >> 3) * 256 + threadIdx.x;   // rank within shard
    for (int e = r; e < NE; e += FBLK * 256) {
        int d = dst[e];
        if (d >= lo && d < hi) {
            int rk = atomicAdd(&deg[d], 1);
            if (rk < CAP) csrB[(size_t)d * CAP + rk] = src[e];
        }
    }
}

// gather (bf16 input rows): u[i] = x[i] + sum_nbr x[s]; 8 lanes/node, uint4 (8 bf16) each
__global__ __launch_bounds__(256) void k_agg8(const uint4* __restrict__ xb, float* __restrict__ u,
                                              const int* __restrict__ deg, const int* __restrict__ csrB) {
    int gid = blockIdx.x * 256 + threadIdx.x;
    int node = gid >> 3;
    if (node >= NN) return;
    int c = gid & 7;
    uint4 sv = xb[(size_t)node * 8 + c];
    float a0 = bf_lo(sv.x), a1 = bf_hi(sv.x), a2 = bf_lo(sv.y), a3 = bf_hi(sv.y);
    float a4 = bf_lo(sv.z), a5 = bf_hi(sv.z), a6 = bf_lo(sv.w), a7 = bf_hi(sv.w);
    int cnt = deg[node]; if (cnt > CAP) cnt = CAP;
    const int* row = csrB + (size_t)node * CAP;
    int e = 0;
    for (; e + 4 <= cnt; e += 4) {
        int s0 = row[e], s1 = row[e + 1], s2 = row[e + 2], s3 = row[e + 3];
        uint4 v0 = xb[(size_t)s0 * 8 + c];
        uint4 v1 = xb[(size_t)s1 * 8 + c];
        uint4 v2 = xb[(size_t)s2 * 8 + c];
        uint4 v3 = xb[(size_t)s3 * 8 + c];
        a0 += (bf_lo(v0.x) + bf_lo(v1.x)) + (bf_lo(v2.x) + bf_lo(v3.x));
        a1 += (bf_hi(v0.x) + bf_hi(v1.x)) + (bf_hi(v2.x) + bf_hi(v3.x));
        a2 += (bf_lo(v0.y) + bf_lo(v1.y)) + (bf_lo(v2.y) + bf_lo(v3.y));
        a3 += (bf_hi(v0.y) + bf_hi(v1.y)) + (bf_hi(v2.y) + bf_hi(v3.y));
        a4 += (bf_lo(v0.z) + bf_lo(v1.z)) + (bf_lo(v2.z) + bf_lo(v3.z));
        a5 += (bf_hi(v0.z) + bf_hi(v1.z)) + (bf_hi(v2.z) + bf_hi(v3.z));
        a6 += (bf_lo(v0.w) + bf_lo(v1.w)) + (bf_lo(v2.w) + bf_lo(v3.w));
        a7 += (bf_hi(v0.w) + bf_hi(v1.w)) + (bf_hi(v2.w) + bf_hi(v3.w));
    }
    for (; e < cnt; ++e) {
        uint4 v = xb[(size_t)row[e] * 8 + c];
        a0 += bf_lo(v.x); a1 += bf_hi(v.x); a2 += bf_lo(v.y); a3 += bf_hi(v.y);
        a4 += bf_lo(v.z); a5 += bf_hi(v.z); a6 += bf_lo(v.w); a7 += bf_hi(v.w);
    }
    float4* u4 = reinterpret_cast<float4*>(u);
    u4[(size_t)node * 16 + 2 * c]     = make_float4(a0, a1, a2, a3);
    u4[(size_t)node * 16 + 2 * c + 1] = make_float4(a4, a5, a6, a7);
}

// MLP + pool: h_bf16 = relu( relu(BN(u @ W1 + b1)) @ W2 + b2 ); pool into p (atomic per segment)
__global__ __launch_bounds__(256) void k_mlp(const float* __restrict__ u, uint2* __restrict__ hout,
                                             const int* __restrict__ batch, float* __restrict__ p, int layer,
                                             const float* __restrict__ W1, const float* __restrict__ b1,
                                             const float* __restrict__ gamma, const float* __restrict__ beta,
                                             const float* __restrict__ rm, const float* __restrict__ rv,
                                             const float* __restrict__ W2, const float* __restrict__ b2) {
    __shared__ __align__(16) float sW1[64][68];
    __shared__ __align__(16) float sW2[64][68];
    __shared__ __align__(16) float sUT[64][68];   // input^T, then intermediate^T, then output [row][col]
    __shared__ float ssc[64], sb1[64], sb2[64];
    __shared__ int sbatch[64];
    const int t = threadIdx.x;
    const int base = blockIdx.x * 64;

    if (t < 64) {
        float sc = gamma[t] * rsqrtf(rv[t] + BN_EPS);
        ssc[t] = sc;
        sb1[t] = (b1[t] - rm[t]) * sc + beta[t];
        sb2[t] = b2[t];
        int row = base + t;
        sbatch[t] = (row < NN) ? batch[row] : -1;
    }
    __syncthreads();
#pragma unroll
    for (int s = 0; s < 16; ++s) {
        int i = t + 256 * s;
        int k = i >> 6, j = i & 63;
        sW1[k][j] = W1[i] * ssc[j];
        sW2[k][j] = W2[i];
    }
    const float4* u4 = reinterpret_cast<const float4*>(u);
#pragma unroll
    for (int s = 0; s < 4; ++s) {
        int i4 = t + 256 * s;
        int r = i4 >> 4, c = i4 & 15;
        int row = base + r;
        float4 v = (row < NN) ? u4[(size_t)row * 16 + c] : make_float4(0.f, 0.f, 0.f, 0.f);
        sUT[c * 4 + 0][r] = v.x; sUT[c * 4 + 1][r] = v.y;
        sUT[c * 4 + 2][r] = v.z; sUT[c * 4 + 3][r] = v.w;
    }
    __syncthreads();

    const int rg4 = (t >> 4) * 4;
    const int cg4 = (t & 15) * 4;
    float acc[4][4];
#pragma unroll
    for (int m = 0; m < 4; ++m)
#pragma unroll
        for (int cc = 0; cc < 4; ++cc) acc[m][cc] = sb1[cg4 + cc];

#pragma unroll 8
    for (int k = 0; k < 64; ++k) {
        float4 a = *reinterpret_cast<const float4*>(&sUT[k][rg4]);
        float4 b = *reinterpret_cast<const float4*>(&sW1[k][cg4]);
        float av[4] = {a.x, a.y, a.z, a.w};
        float bv[4] = {b.x, b.y, b.z, b.w};
#pragma unroll
        for (int m = 0; m < 4; ++m)
#pragma unroll
            for (int cc = 0; cc < 4; ++cc) acc[m][cc] = fmaf(av[m], bv[cc], acc[m][cc]);
    }
    __syncthreads();
#pragma unroll
    for (int cc = 0; cc < 4; ++cc)
#pragma unroll
        for (int m = 0; m < 4; ++m)
            sUT[cg4 + cc][rg4 + m] = fmaxf(acc[m][cc], 0.f);
    __syncthreads();

#pragma unroll
    for (int m = 0; m < 4; ++m)
#pragma unroll
        for (int cc = 0; cc < 4; ++cc) acc[m][cc] = sb2[cg4 + cc];

#pragma unroll 8
    for (int k = 0; k < 64; ++k) {
        float4 a = *reinterpret_cast<const float4*>(&sUT[k][rg4]);
        float4 b = *reinterpret_cast<const float4*>(&sW2[k][cg4]);
        float av[4] = {a.x, a.y, a.z, a.w};
        float bv[4] = {b.x, b.y, b.z, b.w};
#pragma unroll
        for (int m = 0; m < 4; ++m)
#pragma unroll
            for (int cc = 0; cc < 4; ++cc) acc[m][cc] = fmaf(av[m], bv[cc], acc[m][cc]);
    }
    __syncthreads();   // sUT reads done; reuse as [row][col] output stage
#pragma unroll
    for (int m = 0; m < 4; ++m) {
        int row = base + rg4 + m;
        float o0 = fmaxf(acc[m][0], 0.f), o1 = fmaxf(acc[m][1], 0.f);
        float o2 = fmaxf(acc[m][2], 0.f), o3 = fmaxf(acc[m][3], 0.f);
        if (row < NN) {
            uint2 hv; hv.x = bpack(o0, o1); hv.y = bpack(o2, o3);
            hout[(size_t)row * 16 + (t & 15)] = hv;
        }
        sUT[rg4 + m][cg4 + 0] = o0; sUT[rg4 + m][cg4 + 1] = o1;
        sUT[rg4 + m][cg4 + 2] = o2; sUT[rg4 + m][cg4 + 3] = o3;
    }
    __syncthreads();

    if (t < 64) {
        const int j = t;
        float pa = 0.f;
        int gprev = -1;
        for (int r = 0; r < 64; ++r) {
            int row = base + r;
            if (row >= NN) break;
            int g = sbatch[r];
            if (g != gprev) {
                if (gprev >= 0) atomicAdd(&p[gprev * 192 + layer * 64 + j], pa);
                pa = 0.f; gprev = g;
            }
            pa += sUT[r][j];
        }
        if (gprev >= 0) atomicAdd(&p[gprev * 192 + layer * 64 + j], pa);
    }
}

__global__ __launch_bounds__(192) void k_final(const float* __restrict__ p,
                                               const float* __restrict__ W1, const float* __restrict__ b1,
                                               const float* __restrict__ W2, const float* __restrict__ b2,
                                               float* __restrict__ out) {
    int g = blockIdx.x, t = threadIdx.x;
    __shared__ float hg[192];
    __shared__ float y1[192];
    __shared__ float y2[2];
    hg[t] = p[g * 192 + t];
    __syncthreads();
    float acc = b1[t];
    for (int k = 0; k < 192; ++k) acc = fmaf(hg[k], W1[k * 192 + t], acc);
    y1[t] = fmaxf(acc, 0.f);
    __syncthreads();
    if (t < 2) {
        float a = b2[t];
        for (int k = 0; k < 192; ++k) a = fmaf(y1[k], W2[k * 2 + t], a);
        y2[t] = a;
    }
    __syncthreads();
    if (t < 2) {
        float m = fmaxf(y2[0], y2[1]);
        float s = expf(y2[0] - m) + expf(y2[1] - m);
        out[g * 2 + t] = y2[t];
        out[NG * 2 + g * 2 + t] = expf(y2[t] - m) / s;
    }
}

extern "C" void kernel_launch(void* const* d_in, const int* in_sizes, int n_in,
                              void* d_out, int out_size, void* d_ws, size_t ws_size,
                              hipStream_t stream) {
    const float* x    = (const float*)d_in[0];
    const int* ei     = (const int*)d_in[1];
    const int* batch  = (const int*)d_in[2];
    const int* src    = ei;
    const int* dst    = ei + NE;
    const float* lin1_W = (const float*)d_in[27];
    const float* lin1_b = (const float*)d_in[28];
    const float* lin2_W = (const float*)d_in[29];
    const float* lin2_b = (const float*)d_in[30];

    // ws layout (total = 71,193,216 B, bound proven available in rounds 3-8):
    char* w = (char*)d_ws;
    int*   deg  = (int*)w;                                   //   400,000
    float* p    = (float*)(w + 400000);                      //   393,216
    float* u    = (float*)(w + 793216);                      // 25,600,000 fp32 [NN][64]
    char*  xbhB = w + 26393216;                              // 12,800,000 bf16: x_bf, later hB
    char*  hA   = w + 39193216;                              // 12,800,000 bf16
    int*   csrB = (int*)(w + 51993216);                      // 19,200,000 [NN][CAP]

    // zero deg + p (contiguous)
    k_zero_int<<<(198304 + 255) / 256, 256, 0, stream>>>(deg, 198304);
    // x -> bf16
    k_cvt<<<(NN * 8 + 255) / 256, 256, 0, stream>>>((const float4*)x, (uint4*)xbhB, NN * 8);
    // XCD-sharded CSR build
    k_fills<<<8 * FBLK, 256, 0, stream>>>(src, dst, deg, csrB);

    const uint4* gin[3]  = { (const uint4*)xbhB, (const uint4*)hA, (const uint4*)xbhB };
    uint2*       gout[3] = { (uint2*)hA,         (uint2*)xbhB,     (uint2*)hA };
    for (int l = 0; l < 3; ++l) {
        const float* W1 = (const float*)d_in[3 + 8 * l + 0];
        const float* b1 = (const float*)d_in[3 + 8 * l + 1];
        const float* ga = (const float*)d_in[3 + 8 * l + 2];
        const float* be = (const float*)d_in[3 + 8 * l + 3];
        const float* rm = (const float*)d_in[3 + 8 * l + 4];
        const float* rv = (const float*)d_in[3 + 8 * l + 5];
        const float* W2 = (const float*)d_in[3 + 8 * l + 6];
        const float* b2 = (const float*)d_in[3 + 8 * l + 7];

        k_agg8<<<(NN * 8 + 255) / 256, 256, 0, stream>>>(gin[l], u, deg, csrB);
        k_mlp<<<(NN + 63) / 64, 256, 0, stream>>>(u, gout[l], batch, p, l,
                                                  W1, b1, ga, be, rm, rv, W2, b2);
    }
    k_final<<<NG, 192, 0, stream>>>(p, lin1_W, lin1_b, lin2_W, lin2_b, (float*)d_out);
}

// Round 10
// 297.166 us; speedup vs baseline: 1.1638x; 1.0455x over previous
//
#include <hip/hip_runtime.h>

#define NN 100000
#define NE 1200000
#define HD 64
#define NG 512
#define BN_EPS 1e-5f
#define CAP 48          // max degree; P(Poisson(12) >= 48) ~ 6e-17 per node
#define SLICE 12500     // NN/8 dst-nodes per XCD shard
#define FBLK 256        // blocks per shard (grid = 8*FBLK, 8 blocks/CU)

__device__ __forceinline__ float bf_lo(unsigned v) { return __uint_as_float(v << 16); }
__device__ __forceinline__ float bf_hi(unsigned v) { return __uint_as_float(v & 0xffff0000u); }
__device__ __forceinline__ unsigned bpack(float a, float b) {
    unsigned ua = __float_as_uint(a), ub = __float_as_uint(b);
    ua = (ua + 0x7fffu + ((ua >> 16) & 1u)) >> 16;
    ub = (ub + 0x7fffu + ((ub >> 16) & 1u)) >> 16;
    return ua | (ub << 16);
}

__global__ __launch_bounds__(256) void k_zero_int(int* __restrict__ a, int n) {
    int i = blockIdx.x * 256 + threadIdx.x;
    if (i < n) a[i] = 0;
}

// x fp32 -> bf16 (packed pairs), 8 floats/thread
__global__ __launch_bounds__(256) void k_cvt(const float4* __restrict__ xf, uint4* __restrict__ xb, int n4) {
    int i = blockIdx.x * 256 + threadIdx.x;
    if (i < n4) {
        float4 f0 = xf[2 * i], f1 = xf[2 * i + 1];
        uint4 o;
        o.x = bpack(f0.x, f0.y); o.y = bpack(f0.z, f0.w);
        o.z = bpack(f1.x, f1.y); o.w = bpack(f1.z, f1.w);
        xb[i] = o;
    }
}

// XCD-sharded CSR build, int4-vectorized scan: group g (= blockIdx&7) keeps
// only dst in its 12500-node slice; 4 edges per load, 8 blocks/CU.
__global__ __launch_bounds__(256) void k_fills(const int* __restrict__ src, const int4* __restrict__ dst4,
                                               int* __restrict__ deg, int* __restrict__ csrB) {
    const int g = blockIdx.x & 7;
    const int lo = g * SLICE, hi = lo + SLICE;
    const int r = (blockIdx.x >> 3) * 256 + threadIdx.x;
    const int NQ = NE / 4;
    for (int q = r; q < NQ; q += FBLK * 256) {
        int4 d = dst4[q];
        int e = q * 4;
        if (d.x >= lo && d.x < hi) { int rk = atomicAdd(&deg[d.x], 1); if (rk < CAP) csrB[(size_t)d.x * CAP + rk] = src[e]; }
        if (d.y >= lo && d.y < hi) { int rk = atomicAdd(&deg[d.y], 1); if (rk < CAP) csrB[(size_t)d.y * CAP + rk] = src[e + 1]; }
        if (d.z >= lo && d.z < hi) { int rk = atomicAdd(&deg[d.z], 1); if (rk < CAP) csrB[(size_t)d.z * CAP + rk] = src[e + 2]; }
        if (d.w >= lo && d.w < hi) { int rk = atomicAdd(&deg[d.w], 1); if (rk < CAP) csrB[(size_t)d.w * CAP + rk] = src[e + 3]; }
    }
}

// gather (bf16 rows in AND out): u[i] = x[i] + sum_nbr x[s]; 8 lanes/node
__global__ __launch_bounds__(256) void k_agg8(const uint4* __restrict__ xb, uint4* __restrict__ u,
                                              const int* __restrict__ deg, const int* __restrict__ csrB) {
    int gid = blockIdx.x * 256 + threadIdx.x;
    int node = gid >> 3;
    if (node >= NN) return;
    int c = gid & 7;
    uint4 sv = xb[(size_t)node * 8 + c];
    float a0 = bf_lo(sv.x), a1 = bf_hi(sv.x), a2 = bf_lo(sv.y), a3 = bf_hi(sv.y);
    float a4 = bf_lo(sv.z), a5 = bf_hi(sv.z), a6 = bf_lo(sv.w), a7 = bf_hi(sv.w);
    int cnt = deg[node]; if (cnt > CAP) cnt = CAP;
    const int* row = csrB + (size_t)node * CAP;
    int e = 0;
    for (; e + 4 <= cnt; e += 4) {
        int s0 = row[e], s1 = row[e + 1], s2 = row[e + 2], s3 = row[e + 3];
        uint4 v0 = xb[(size_t)s0 * 8 + c];
        uint4 v1 = xb[(size_t)s1 * 8 + c];
        uint4 v2 = xb[(size_t)s2 * 8 + c];
        uint4 v3 = xb[(size_t)s3 * 8 + c];
        a0 += (bf_lo(v0.x) + bf_lo(v1.x)) + (bf_lo(v2.x) + bf_lo(v3.x));
        a1 += (bf_hi(v0.x) + bf_hi(v1.x)) + (bf_hi(v2.x) + bf_hi(v3.x));
        a2 += (bf_lo(v0.y) + bf_lo(v1.y)) + (bf_lo(v2.y) + bf_lo(v3.y));
        a3 += (bf_hi(v0.y) + bf_hi(v1.y)) + (bf_hi(v2.y) + bf_hi(v3.y));
        a4 += (bf_lo(v0.z) + bf_lo(v1.z)) + (bf_lo(v2.z) + bf_lo(v3.z));
        a5 += (bf_hi(v0.z) + bf_hi(v1.z)) + (bf_hi(v2.z) + bf_hi(v3.z));
        a6 += (bf_lo(v0.w) + bf_lo(v1.w)) + (bf_lo(v2.w) + bf_lo(v3.w));
        a7 += (bf_hi(v0.w) + bf_hi(v1.w)) + (bf_hi(v2.w) + bf_hi(v3.w));
    }
    for (; e < cnt; ++e) {
        uint4 v = xb[(size_t)row[e] * 8 + c];
        a0 += bf_lo(v.x); a1 += bf_hi(v.x); a2 += bf_lo(v.y); a3 += bf_hi(v.y);
        a4 += bf_lo(v.z); a5 += bf_hi(v.z); a6 += bf_lo(v.w); a7 += bf_hi(v.w);
    }
    uint4 o;
    o.x = bpack(a0, a1); o.y = bpack(a2, a3); o.z = bpack(a4, a5); o.w = bpack(a6, a7);
    u[(size_t)node * 8 + c] = o;
}

// MLP + pool: h_bf16 = relu( relu(BN(u @ W1 + b1)) @ W2 + b2 ); u is bf16 rows.
__global__ __launch_bounds__(256) void k_mlp(const uint4* __restrict__ ub, uint2* __restrict__ hout,
                                             const int* __restrict__ batch, float* __restrict__ p, int layer,
                                             const float* __restrict__ W1, const float* __restrict__ b1,
                                             const float* __restrict__ gamma, const float* __restrict__ beta,
                                             const float* __restrict__ rm, const float* __restrict__ rv,
                                             const float* __restrict__ W2, const float* __restrict__ b2) {
    __shared__ __align__(16) float sW1[64][68];
    __shared__ __align__(16) float sW2[64][68];
    __shared__ __align__(16) float sUT[64][68];   // input^T, then intermediate^T, then output [row][col]
    __shared__ float ssc[64], sb1[64], sb2[64];
    __shared__ int sbatch[64];
    const int t = threadIdx.x;
    const int base = blockIdx.x * 64;

    if (t < 64) {
        float sc = gamma[t] * rsqrtf(rv[t] + BN_EPS);
        ssc[t] = sc;
        sb1[t] = (b1[t] - rm[t]) * sc + beta[t];
        sb2[t] = b2[t];
        int row = base + t;
        sbatch[t] = (row < NN) ? batch[row] : -1;
    }
    __syncthreads();
#pragma unroll
    for (int s = 0; s < 16; ++s) {
        int i = t + 256 * s;
        int k = i >> 6, j = i & 63;
        sW1[k][j] = W1[i] * ssc[j];
        sW2[k][j] = W2[i];
    }
    // load u (bf16): lane = row (r = t&63), wave picks chunk c; LDS writes 2-way-free
#pragma unroll
    for (int s = 0; s < 2; ++s) {
        int i4 = t + 256 * s;
        int r = i4 & 63, c = i4 >> 6;      // c in 0..7 across s
        int row = base + r;
        uint4 v = (row < NN) ? ub[(size_t)row * 8 + c] : make_uint4(0u, 0u, 0u, 0u);
        sUT[c * 8 + 0][r] = bf_lo(v.x); sUT[c * 8 + 1][r] = bf_hi(v.x);
        sUT[c * 8 + 2][r] = bf_lo(v.y); sUT[c * 8 + 3][r] = bf_hi(v.y);
        sUT[c * 8 + 4][r] = bf_lo(v.z); sUT[c * 8 + 5][r] = bf_hi(v.z);
        sUT[c * 8 + 6][r] = bf_lo(v.w); sUT[c * 8 + 7][r] = bf_hi(v.w);
    }
    __syncthreads();

    const int rg4 = (t >> 4) * 4;
    const int cg4 = (t & 15) * 4;
    float acc[4][4];
#pragma unroll
    for (int m = 0; m < 4; ++m)
#pragma unroll
        for (int cc = 0; cc < 4; ++cc) acc[m][cc] = sb1[cg4 + cc];

#pragma unroll 8
    for (int k = 0; k < 64; ++k) {
        float4 a = *reinterpret_cast<const float4*>(&sUT[k][rg4]);
        float4 b = *reinterpret_cast<const float4*>(&sW1[k][cg4]);
        float av[4] = {a.x, a.y, a.z, a.w};
        float bv[4] = {b.x, b.y, b.z, b.w};
#pragma unroll
        for (int m = 0; m < 4; ++m)
#pragma unroll
            for (int cc = 0; cc < 4; ++cc) acc[m][cc] = fmaf(av[m], bv[cc], acc[m][cc]);
    }
    __syncthreads();
#pragma unroll
    for (int cc = 0; cc < 4; ++cc)
#pragma unroll
        for (int m = 0; m < 4; ++m)
            sUT[cg4 + cc][rg4 + m] = fmaxf(acc[m][cc], 0.f);
    __syncthreads();

#pragma unroll
    for (int m = 0; m < 4; ++m)
#pragma unroll
        for (int cc = 0; cc < 4; ++cc) acc[m][cc] = sb2[cg4 + cc];

#pragma unroll 8
    for (int k = 0; k < 64; ++k) {
        float4 a = *reinterpret_cast<const float4*>(&sUT[k][rg4]);
        float4 b = *reinterpret_cast<const float4*>(&sW2[k][cg4]);
        float av[4] = {a.x, a.y, a.z, a.w};
        float bv[4] = {b.x, b.y, b.z, b.w};
#pragma unroll
        for (int m = 0; m < 4; ++m)
#pragma unroll
            for (int cc = 0; cc < 4; ++cc) acc[m][cc] = fmaf(av[m], bv[cc], acc[m][cc]);
    }
    __syncthreads();   // sUT reads done; reuse as [row][col] output stage
#pragma unroll
    for (int m = 0; m < 4; ++m) {
        int row = base + rg4 + m;
        float o0 = fmaxf(acc[m][0], 0.f), o1 = fmaxf(acc[m][1], 0.f);
        float o2 = fmaxf(acc[m][2], 0.f), o3 = fmaxf(acc[m][3], 0.f);
        if (row < NN) {
            uint2 hv; hv.x = bpack(o0, o1); hv.y = bpack(o2, o3);
            hout[(size_t)row * 16 + (t & 15)] = hv;
        }
        sUT[rg4 + m][cg4 + 0] = o0; sUT[rg4 + m][cg4 + 1] = o1;
        sUT[rg4 + m][cg4 + 2] = o2; sUT[rg4 + m][cg4 + 3] = o3;
    }
    __syncthreads();

    if (t < 64) {
        const int j = t;
        float pa = 0.f;
        int gprev = -1;
        for (int r = 0; r < 64; ++r) {
            int row = base + r;
            if (row >= NN) break;
            int g = sbatch[r];
            if (g != gprev) {
                if (gprev >= 0) atomicAdd(&p[gprev * 192 + layer * 64 + j], pa);
                pa = 0.f; gprev = g;
            }
            pa += sUT[r][j];
        }
        if (gprev >= 0) atomicAdd(&p[gprev * 192 + layer * 64 + j], pa);
    }
}

__global__ __launch_bounds__(192) void k_final(const float* __restrict__ p,
                                               const float* __restrict__ W1, const float* __restrict__ b1,
                                               const float* __restrict__ W2, const float* __restrict__ b2,
                                               float* __restrict__ out) {
    int g = blockIdx.x, t = threadIdx.x;
    __shared__ float hg[192];
    __shared__ float y1[192];
    __shared__ float y2[2];
    hg[t] = p[g * 192 + t];
    __syncthreads();
    float acc = b1[t];
    for (int k = 0; k < 192; ++k) acc = fmaf(hg[k], W1[k * 192 + t], acc);
    y1[t] = fmaxf(acc, 0.f);
    __syncthreads();
    if (t < 2) {
        float a = b2[t];
        for (int k = 0; k < 192; ++k) a = fmaf(y1[k], W2[k * 2 + t], a);
        y2[t] = a;
    }
    __syncthreads();
    if (t < 2) {
        float m = fmaxf(y2[0], y2[1]);
        float s = expf(y2[0] - m) + expf(y2[1] - m);
        out[g * 2 + t] = y2[t];
        out[NG * 2 + g * 2 + t] = expf(y2[t] - m) / s;
    }
}

extern "C" void kernel_launch(void* const* d_in, const int* in_sizes, int n_in,
                              void* d_out, int out_size, void* d_ws, size_t ws_size,
                              hipStream_t stream) {
    const float* x    = (const float*)d_in[0];
    const int* ei     = (const int*)d_in[1];
    const int* batch  = (const int*)d_in[2];
    const int* src    = ei;
    const int* dst    = ei + NE;
    const float* lin1_W = (const float*)d_in[27];
    const float* lin1_b = (const float*)d_in[28];
    const float* lin2_W = (const float*)d_in[29];
    const float* lin2_b = (const float*)d_in[30];

    // ws layout (total <= 71,193,216 B, bound proven available in rounds 3-9):
    char* w = (char*)d_ws;
    int*   deg  = (int*)w;                                   //   400,000
    float* p    = (float*)(w + 400000);                      //   393,216
    char*  u    = w + 793216;                                // 12,800,000 bf16 [NN][64]
    char*  xbhB = w + 26393216;                              // 12,800,000 bf16: x_bf, later hB
    char*  hA   = w + 39193216;                              // 12,800,000 bf16
    int*   csrB = (int*)(w + 51993216);                      // 19,200,000 [NN][CAP]
    (void)u;

    // zero deg + p (contiguous)
    k_zero_int<<<(198304 + 255) / 256, 256, 0, stream>>>(deg, 198304);
    // x -> bf16
    k_cvt<<<(NN * 8 + 255) / 256, 256, 0, stream>>>((const float4*)x, (uint4*)xbhB, NN * 8);
    // XCD-sharded CSR build, vectorized scan
    k_fills<<<8 * FBLK, 256, 0, stream>>>(src, (const int4*)dst, deg, csrB);

    const uint4* gin[3]  = { (const uint4*)xbhB, (const uint4*)hA, (const uint4*)xbhB };
    uint2*       gout[3] = { (uint2*)hA,         (uint2*)xbhB,     (uint2*)hA };
    for (int l = 0; l < 3; ++l) {
        const float* W1 = (const float*)d_in[3 + 8 * l + 0];
        const float* b1 = (const float*)d_in[3 + 8 * l + 1];
        const float* ga = (const float*)d_in[3 + 8 * l + 2];
        const float* be = (const float*)d_in[3 + 8 * l + 3];
        const float* rm = (const float*)d_in[3 + 8 * l + 4];
        const float* rv = (const float*)d_in[3 + 8 * l + 5];
        const float* W2 = (const float*)d_in[3 + 8 * l + 6];
        const float* b2 = (const float*)d_in[3 + 8 * l + 7];

        k_agg8<<<(NN * 8 + 255) / 256, 256, 0, stream>>>(gin[l], (uint4*)u, deg, csrB);
        k_mlp<<<(NN + 63) / 64, 256, 0, stream>>>((const uint4*)u, gout[l], batch, p, l,
                                                  W1, b1, ga, be, rm, rv, W2, b2);
    }
    k_final<<<NG, 192, 0, stream>>>(p, lin1_W, lin1_b, lin2_W, lin2_b, (float*)d_out);
}

// Round 11
// 245.550 us; speedup vs baseline: 1.4084x; 1.2102x over previous
//
#include <hip/hip_runtime.h>

#define NN 100000
#define NE 1200000
#define HD 64
#define NG 512
#define BN_EPS 1e-5f
#define CAP 48          // max degree; P(Poisson(12) >= 48) ~ 6e-17 per node
#define SLICE 12500     // NN/8 dst-nodes per XCD shard
#define FBLK 256        // blocks per shard (grid = 8*FBLK)

typedef int   v4i    __attribute__((ext_vector_type(4)));
typedef short bf16x8 __attribute__((ext_vector_type(8)));
typedef float f32x4  __attribute__((ext_vector_type(4)));

__device__ __forceinline__ float bf_lo(unsigned v) { return __uint_as_float(v << 16); }
__device__ __forceinline__ float bf_hi(unsigned v) { return __uint_as_float(v & 0xffff0000u); }
__device__ __forceinline__ unsigned bpack(float a, float b) {
    unsigned ua = __float_as_uint(a), ub = __float_as_uint(b);
    ua = (ua + 0x7fffu + ((ua >> 16) & 1u)) >> 16;
    ub = (ub + 0x7fffu + ((ub >> 16) & 1u)) >> 16;
    return ua | (ub << 16);
}
__device__ __forceinline__ short bf1(float a) {
    unsigned ua = __float_as_uint(a);
    return (short)((ua + 0x7fffu + ((ua >> 16) & 1u)) >> 16);
}

__global__ __launch_bounds__(256) void k_zero_int(int* __restrict__ a, int n) {
    int i = blockIdx.x * 256 + threadIdx.x;
    if (i < n) a[i] = 0;
}

// x fp32 -> bf16 (packed pairs), 8 floats/thread
__global__ __launch_bounds__(256) void k_cvt(const float4* __restrict__ xf, uint4* __restrict__ xb, int n4) {
    int i = blockIdx.x * 256 + threadIdx.x;
    if (i < n4) {
        float4 f0 = xf[2 * i], f1 = xf[2 * i + 1];
        uint4 o;
        o.x = bpack(f0.x, f0.y); o.y = bpack(f0.z, f0.w);
        o.z = bpack(f1.x, f1.y); o.w = bpack(f1.z, f1.w);
        xb[i] = o;
    }
}

// XCD-sharded CSR build; NT loads keep the streaming edge data from evicting
// the dirty csrB lines out of each XCD's L2 (write-merge protection).
__global__ __launch_bounds__(256) void k_fills(const int* __restrict__ src, const v4i* __restrict__ dst4,
                                               int* __restrict__ deg, int* __restrict__ csrB) {
    const int g = blockIdx.x & 7;
    const int lo = g * SLICE, hi = lo + SLICE;
    const int r = (blockIdx.x >> 3) * 256 + threadIdx.x;
    const int NQ = NE / 4;
    for (int q = r; q < NQ; q += FBLK * 256) {
        v4i d = __builtin_nontemporal_load(&dst4[q]);
        int e = q * 4;
        if (d.x >= lo && d.x < hi) { int rk = atomicAdd(&deg[d.x], 1); if (rk < CAP) csrB[(size_t)d.x * CAP + rk] = __builtin_nontemporal_load(&src[e]); }
        if (d.y >= lo && d.y < hi) { int rk = atomicAdd(&deg[d.y], 1); if (rk < CAP) csrB[(size_t)d.y * CAP + rk] = __builtin_nontemporal_load(&src[e + 1]); }
        if (d.z >= lo && d.z < hi) { int rk = atomicAdd(&deg[d.z], 1); if (rk < CAP) csrB[(size_t)d.z * CAP + rk] = __builtin_nontemporal_load(&src[e + 2]); }
        if (d.w >= lo && d.w < hi) { int rk = atomicAdd(&deg[d.w], 1); if (rk < CAP) csrB[(size_t)d.w * CAP + rk] = __builtin_nontemporal_load(&src[e + 3]); }
    }
}

// gather (bf16 rows in AND out): u[i] = x[i] + sum_nbr x[s]; 8 lanes/node
__global__ __launch_bounds__(256) void k_agg8(const uint4* __restrict__ xb, uint4* __restrict__ u,
                                              const int* __restrict__ deg, const int* __restrict__ csrB) {
    int gid = blockIdx.x * 256 + threadIdx.x;
    int node = gid >> 3;
    if (node >= NN) return;
    int c = gid & 7;
    uint4 sv = xb[(size_t)node * 8 + c];
    float a0 = bf_lo(sv.x), a1 = bf_hi(sv.x), a2 = bf_lo(sv.y), a3 = bf_hi(sv.y);
    float a4 = bf_lo(sv.z), a5 = bf_hi(sv.z), a6 = bf_lo(sv.w), a7 = bf_hi(sv.w);
    int cnt = deg[node]; if (cnt > CAP) cnt = CAP;
    const int* row = csrB + (size_t)node * CAP;
    int e = 0;
    for (; e + 4 <= cnt; e += 4) {
        int s0 = row[e], s1 = row[e + 1], s2 = row[e + 2], s3 = row[e + 3];
        uint4 v0 = xb[(size_t)s0 * 8 + c];
        uint4 v1 = xb[(size_t)s1 * 8 + c];
        uint4 v2 = xb[(size_t)s2 * 8 + c];
        uint4 v3 = xb[(size_t)s3 * 8 + c];
        a0 += (bf_lo(v0.x) + bf_lo(v1.x)) + (bf_lo(v2.x) + bf_lo(v3.x));
        a1 += (bf_hi(v0.x) + bf_hi(v1.x)) + (bf_hi(v2.x) + bf_hi(v3.x));
        a2 += (bf_lo(v0.y) + bf_lo(v1.y)) + (bf_lo(v2.y) + bf_lo(v3.y));
        a3 += (bf_hi(v0.y) + bf_hi(v1.y)) + (bf_hi(v2.y) + bf_hi(v3.y));
        a4 += (bf_lo(v0.z) + bf_lo(v1.z)) + (bf_lo(v2.z) + bf_lo(v3.z));
        a5 += (bf_hi(v0.z) + bf_hi(v1.z)) + (bf_hi(v2.z) + bf_hi(v3.z));
        a6 += (bf_lo(v0.w) + bf_lo(v1.w)) + (bf_lo(v2.w) + bf_lo(v3.w));
        a7 += (bf_hi(v0.w) + bf_hi(v1.w)) + (bf_hi(v2.w) + bf_hi(v3.w));
    }
    for (; e < cnt; ++e) {
        uint4 v = xb[(size_t)row[e] * 8 + c];
        a0 += bf_lo(v.x); a1 += bf_hi(v.x); a2 += bf_lo(v.y); a3 += bf_hi(v.y);
        a4 += bf_lo(v.z); a5 += bf_hi(v.z); a6 += bf_lo(v.w); a7 += bf_hi(v.w);
    }
    uint4 o;
    o.x = bpack(a0, a1); o.y = bpack(a2, a3); o.z = bpack(a4, a5); o.w = bpack(a6, a7);
    u[(size_t)node * 8 + c] = o;
}

// Pre-pack weights into MFMA B-frag layout (bf16, BN folded into W1/b1).
// wf[g*2048 + ((c*2+h)*64 + l)*4 + w] = bpack(W[k0][col], W[k0+1][col]),
// k0 = h*32 + (l>>4)*8 + 2w, col = c*16 + (l&15). bias[0..63]=b1', [64..127]=b2.
__global__ __launch_bounds__(256) void k_wprep(const float* __restrict__ W1, const float* __restrict__ b1,
                                               const float* __restrict__ gamma, const float* __restrict__ beta,
                                               const float* __restrict__ rm, const float* __restrict__ rv,
                                               const float* __restrict__ W2, const float* __restrict__ b2,
                                               unsigned* __restrict__ wf, float* __restrict__ bias) {
    int t = threadIdx.x;
    __shared__ float ssc[64];
    if (t < 64) {
        float sc = gamma[t] * rsqrtf(rv[t] + BN_EPS);
        ssc[t] = sc;
        bias[t] = (b1[t] - rm[t]) * sc + beta[t];
        bias[64 + t] = b2[t];
    }
    __syncthreads();
    for (int i = 0; i < 16; ++i) {
        int idx = t + 256 * i;           // 0..4095
        int wp = idx & 3;
        int l  = (idx >> 2) & 63;
        int th = (idx >> 8) & 7;         // c*2+h
        int g  = idx >> 11;
        int h  = th & 1;
        int col = (th >> 1) * 16 + (l & 15);
        int k0 = h * 32 + (l >> 4) * 8 + 2 * wp;
        float w0, w1;
        if (g == 0) { w0 = W1[k0 * 64 + col] * ssc[col]; w1 = W1[(k0 + 1) * 64 + col] * ssc[col]; }
        else        { w0 = W2[k0 * 64 + col];            w1 = W2[(k0 + 1) * 64 + col]; }
        wf[idx] = bpack(w0, w1);
    }
}

// MFMA MLP + pool: h = relu(relu(BN(u@W1+b1))@W2+b2), u/h bf16, weights pre-packed.
// 64 rows/block, 4 waves; wave w owns rows 16w..16w+15 (A: row=l&15, k=(l>>4)*8+r;
// C/D: col=l&15, row=(l>>4)*4+r — m89-verified family).
__global__ __launch_bounds__(256) void k_mlp(const uint4* __restrict__ ub, uint4* __restrict__ hout,
                                             const int* __restrict__ batch, float* __restrict__ p, int layer,
                                             const unsigned* __restrict__ wf, const float* __restrict__ bias) {
    __shared__ unsigned sBF[4096];                   // 16 KB: B-frags, both GEMMs
    __shared__ __align__(16) char sMix[64 * 68 * 4]; // 17.4 KB: sTb (bf16) then sOut (fp32)
    __shared__ float sb1[64], sb2[64];
    __shared__ int sbatch[64];
    const int t = threadIdx.x;
    const int base = blockIdx.x * 64;
    const int w = t >> 6, l = t & 63;

    {   // stage B-frags (1024 uint4)
        const uint4* wf4 = (const uint4*)wf;
        uint4* s4 = (uint4*)sBF;
        for (int i = t; i < 1024; i += 256) s4[i] = wf4[i];
    }
    if (t < 64) {
        sb1[t] = bias[t];
        sb2[t] = bias[64 + t];
        int row = base + t;
        sbatch[t] = (row < NN) ? batch[row] : -1;
    }
    // GEMM1 A-frags straight from global u (bf16 rows)
    int rowg = base + 16 * w + (l & 15);
    if (rowg > NN - 1) rowg = NN - 1;
    uint4 a1u = ub[(size_t)rowg * 8 + (l >> 4)];
    uint4 a2u = ub[(size_t)rowg * 8 + 4 + (l >> 4)];
    bf16x8 a1 = *(bf16x8*)&a1u, a2 = *(bf16x8*)&a2u;
    __syncthreads();

    short* sTb = (short*)sMix;                       // [64][72] bf16, 144B row stride
#pragma unroll
    for (int c = 0; c < 4; ++c) {
        f32x4 acc = {0.f, 0.f, 0.f, 0.f};
        uint4 b0u = *(uint4*)&sBF[((c * 2 + 0) * 64 + l) * 4];
        uint4 b1u = *(uint4*)&sBF[((c * 2 + 1) * 64 + l) * 4];
        acc = __builtin_amdgcn_mfma_f32_16x16x32_bf16(a1, *(bf16x8*)&b0u, acc, 0, 0, 0);
        acc = __builtin_amdgcn_mfma_f32_16x16x32_bf16(a2, *(bf16x8*)&b1u, acc, 0, 0, 0);
        int col = c * 16 + (l & 15);
        float bb = sb1[col];
#pragma unroll
        for (int r = 0; r < 4; ++r) {
            int m = 16 * w + (l >> 4) * 4 + r;
            sTb[m * 72 + col] = bf1(fmaxf(acc[r] + bb, 0.f));
        }
    }
    __syncthreads();
    // GEMM2 A-frags from sTb
    int mrow = 16 * w + (l & 15);
    uint4 t1u = *(uint4*)&sTb[mrow * 72 + (l >> 4) * 8];
    uint4 t2u = *(uint4*)&sTb[mrow * 72 + 32 + (l >> 4) * 8];
    bf16x8 ta1 = *(bf16x8*)&t1u, ta2 = *(bf16x8*)&t2u;
    __syncthreads();                                 // sTb reads done; alias as sOut
    float (*sOut)[68] = (float(*)[68])sMix;
#pragma unroll
    for (int c = 0; c < 4; ++c) {
        f32x4 acc = {0.f, 0.f, 0.f, 0.f};
        uint4 b0u = *(uint4*)&sBF[2048 + ((c * 2 + 0) * 64 + l) * 4];
        uint4 b1u = *(uint4*)&sBF[2048 + ((c * 2 + 1) * 64 + l) * 4];
        acc = __builtin_amdgcn_mfma_f32_16x16x32_bf16(ta1, *(bf16x8*)&b0u, acc, 0, 0, 0);
        acc = __builtin_amdgcn_mfma_f32_16x16x32_bf16(ta2, *(bf16x8*)&b1u, acc, 0, 0, 0);
        int col = c * 16 + (l & 15);
        float bb = sb2[col];
#pragma unroll
        for (int r = 0; r < 4; ++r)
            sOut[16 * w + (l >> 4) * 4 + r][col] = fmaxf(acc[r] + bb, 0.f);
    }
    __syncthreads();
    // h write (bf16, coalesced): thread t -> row t>>2, quarter t&3 (16 cols)
    {
        int row = t >> 2, q = t & 3;
        int grow = base + row;
        if (grow < NN) {
            const float* sp = &sOut[row][q * 16];
            uint4 o1, o2;
            o1.x = bpack(sp[0], sp[1]);  o1.y = bpack(sp[2], sp[3]);
            o1.z = bpack(sp[4], sp[5]);  o1.w = bpack(sp[6], sp[7]);
            o2.x = bpack(sp[8], sp[9]);  o2.y = bpack(sp[10], sp[11]);
            o2.z = bpack(sp[12], sp[13]); o2.w = bpack(sp[14], sp[15]);
            hout[(size_t)grow * 8 + 2 * q]     = o1;
            hout[(size_t)grow * 8 + 2 * q + 1] = o2;
        }
    }
    // pool: per-graph segment sums over the block's rows, one atomic per segment
    if (t < 64) {
        const int j = t;
        float pa = 0.f;
        int gprev = -1;
        for (int r = 0; r < 64; ++r) {
            int row = base + r;
            if (row >= NN) break;
            int g = sbatch[r];
            if (g != gprev) {
                if (gprev >= 0) atomicAdd(&p[gprev * 192 + layer * 64 + j], pa);
                pa = 0.f; gprev = g;
            }
            pa += sOut[r][j];
        }
        if (gprev >= 0) atomicAdd(&p[gprev * 192 + layer * 64 + j], pa);
    }
}

__global__ __launch_bounds__(192) void k_final(const float* __restrict__ p,
                                               const float* __restrict__ W1, const float* __restrict__ b1,
                                               const float* __restrict__ W2, const float* __restrict__ b2,
                                               float* __restrict__ out) {
    int g = blockIdx.x, t = threadIdx.x;
    __shared__ float hg[192];
    __shared__ float y1[192];
    __shared__ float y2[2];
    hg[t] = p[g * 192 + t];
    __syncthreads();
    float acc = b1[t];
    for (int k = 0; k < 192; ++k) acc = fmaf(hg[k], W1[k * 192 + t], acc);
    y1[t] = fmaxf(acc, 0.f);
    __syncthreads();
    if (t < 2) {
        float a = b2[t];
        for (int k = 0; k < 192; ++k) a = fmaf(y1[k], W2[k * 2 + t], a);
        y2[t] = a;
    }
    __syncthreads();
    if (t < 2) {
        float m = fmaxf(y2[0], y2[1]);
        float s = expf(y2[0] - m) + expf(y2[1] - m);
        out[g * 2 + t] = y2[t];
        out[NG * 2 + g * 2 + t] = expf(y2[t] - m) / s;
    }
}

extern "C" void kernel_launch(void* const* d_in, const int* in_sizes, int n_in,
                              void* d_out, int out_size, void* d_ws, size_t ws_size,
                              hipStream_t stream) {
    const float* x    = (const float*)d_in[0];
    const int* ei     = (const int*)d_in[1];
    const int* batch  = (const int*)d_in[2];
    const int* src    = ei;
    const int* dst    = ei + NE;
    const float* lin1_W = (const float*)d_in[27];
    const float* lin1_b = (const float*)d_in[28];
    const float* lin2_W = (const float*)d_in[29];
    const float* lin2_b = (const float*)d_in[30];

    // ws layout (total <= 71,193,216 B, bound proven available rounds 3-10):
    char* w = (char*)d_ws;
    int*   deg  = (int*)w;                                   //   400,000
    float* p    = (float*)(w + 400000);                      //   393,216
    char*  u    = w + 793216;                                // 12,800,000 bf16 [NN][64]
    unsigned* wf  = (unsigned*)(w + 13600000);               //    16,384 (hole left by fp32->bf16 u)
    float*    bias= (float*)(w + 13616384);                  //       512
    char*  xbhB = w + 26393216;                              // 12,800,000 bf16: x_bf, later hB
    char*  hA   = w + 39193216;                              // 12,800,000 bf16
    int*   csrB = (int*)(w + 51993216);                      // 19,200,000 [NN][CAP]

    // zero deg + p (contiguous)
    k_zero_int<<<(198304 + 255) / 256, 256, 0, stream>>>(deg, 198304);
    // x -> bf16
    k_cvt<<<(NN * 8 + 255) / 256, 256, 0, stream>>>((const float4*)x, (uint4*)xbhB, NN * 8);
    // XCD-sharded CSR build with NT streaming loads
    k_fills<<<8 * FBLK, 256, 0, stream>>>(src, (const v4i*)dst, deg, csrB);

    const uint4* gin[3]  = { (const uint4*)xbhB, (const uint4*)hA, (const uint4*)xbhB };
    uint4*       gout[3] = { (uint4*)hA,         (uint4*)xbhB,     (uint4*)hA };
    for (int l = 0; l < 3; ++l) {
        const float* W1 = (const float*)d_in[3 + 8 * l + 0];
        const float* b1 = (const float*)d_in[3 + 8 * l + 1];
        const float* ga = (const float*)d_in[3 + 8 * l + 2];
        const float* be = (const float*)d_in[3 + 8 * l + 3];
        const float* rm = (const float*)d_in[3 + 8 * l + 4];
        const float* rv = (const float*)d_in[3 + 8 * l + 5];
        const float* W2 = (const float*)d_in[3 + 8 * l + 6];
        const float* b2 = (const float*)d_in[3 + 8 * l + 7];

        k_wprep<<<1, 256, 0, stream>>>(W1, b1, ga, be, rm, rv, W2, b2, wf, bias);
        k_agg8<<<(NN * 8 + 255) / 256, 256, 0, stream>>>(gin[l], (uint4*)u, deg, csrB);
        k_mlp<<<(NN + 63) / 64, 256, 0, stream>>>((const uint4*)u, gout[l], batch, p, l, wf, bias);
    }
    k_final<<<NG, 192, 0, stream>>>(p, lin1_W, lin1_b, lin2_W, lin2_b, (float*)d_out);
}

// Round 12
// 245.063 us; speedup vs baseline: 1.4112x; 1.0020x over previous
//
#include <hip/hip_runtime.h>

#define NN 100000
#define NE 1200000
#define HD 64
#define NG 512
#define BN_EPS 1e-5f
#define CAP 48          // max degree; P(Poisson(12) >= 48) ~ 6e-17 per node
#define SLICE 12500     // NN/8 dst-nodes per XCD shard
#define ABLK 1024       // pass-A blocks
#define ACHUNK 1172     // ceil(NE/ABLK)
#define BINCAP 256      // per-(block,shard) bin capacity; mean 146.5, +9.7 sigma

typedef short bf16x8 __attribute__((ext_vector_type(8)));
typedef float f32x4  __attribute__((ext_vector_type(4)));

__device__ __forceinline__ float bf_lo(unsigned v) { return __uint_as_float(v << 16); }
__device__ __forceinline__ float bf_hi(unsigned v) { return __uint_as_float(v & 0xffff0000u); }
__device__ __forceinline__ unsigned bpack(float a, float b) {
    unsigned ua = __float_as_uint(a), ub = __float_as_uint(b);
    ua = (ua + 0x7fffu + ((ua >> 16) & 1u)) >> 16;
    ub = (ub + 0x7fffu + ((ub >> 16) & 1u)) >> 16;
    return ua | (ub << 16);
}
__device__ __forceinline__ short bf1(float a) {
    unsigned ua = __float_as_uint(a);
    return (short)((ua + 0x7fffu + ((ua >> 16) & 1u)) >> 16);
}

__global__ __launch_bounds__(256) void k_zero_int(int* __restrict__ a, int n) {
    int i = blockIdx.x * 256 + threadIdx.x;
    if (i < n) a[i] = 0;
}

// x fp32 -> bf16 (packed pairs), 8 floats/thread
__global__ __launch_bounds__(256) void k_cvt(const float4* __restrict__ xf, uint4* __restrict__ xb, int n4) {
    int i = blockIdx.x * 256 + threadIdx.x;
    if (i < n4) {
        float4 f0 = xf[2 * i], f1 = xf[2 * i + 1];
        uint4 o;
        o.x = bpack(f0.x, f0.y); o.y = bpack(f0.z, f0.w);
        o.z = bpack(f1.x, f1.y); o.w = bpack(f1.z, f1.w);
        xb[i] = o;
    }
}

// Pass A: per-block private LDS binning by dst shard; sequential segment writes.
// pack = (dst_local << 17) | src  (dst_local < 12500 < 2^14, src < 2^17)
__global__ __launch_bounds__(256) void k_binA(const int* __restrict__ src, const int* __restrict__ dst,
                                              unsigned* __restrict__ bins, int* __restrict__ bcnt,
                                              int* __restrict__ deg, int* __restrict__ csrB) {
    __shared__ unsigned sb[8][BINCAP];   // 8 KB
    __shared__ int scnt[8];
    const int b = blockIdx.x, t = threadIdx.x;
    if (t < 8) scnt[t] = 0;
    __syncthreads();
    const int e0 = b * ACHUNK;
    int e1 = e0 + ACHUNK; if (e1 > NE) e1 = NE;
    for (int e = e0 + t; e < e1; e += 256) {
        int d = dst[e], s = src[e];
        int g = d / SLICE;
        int pos = atomicAdd(&scnt[g], 1);
        if (pos < BINCAP) {
            sb[g][pos] = ((unsigned)(d - g * SLICE) << 17) | (unsigned)s;
        } else {            // ~never: direct fallback fill
            int rk = atomicAdd(&deg[d], 1);
            if (rk < CAP) csrB[(size_t)d * CAP + rk] = s;
        }
    }
    __syncthreads();
#pragma unroll
    for (int i = t; i < 8 * BINCAP; i += 256) {
        int g = i >> 8, pos = i & (BINCAP - 1);
        int c = scnt[g]; if (c > BINCAP) c = BINCAP;
        if (pos < c) bins[((size_t)b * 8 + g) * BINCAP + pos] = sb[g][pos];
    }
    if (t < 8) {
        int c = scnt[t]; if (c > BINCAP) c = BINCAP;
        bcnt[b * 8 + t] = c;
    }
}

// Pass B: shard g (= blockIdx&7, XCD-affine) drains its segments; scattered
// writes stay in a 2.4MB per-XCD L2 slice with only ~1.2MB streaming reads.
__global__ __launch_bounds__(256) void k_binB(const unsigned* __restrict__ bins, const int* __restrict__ bcnt,
                                              int* __restrict__ deg, int* __restrict__ csrB) {
    const int g = blockIdx.x & 7;
    const int j0 = blockIdx.x >> 3;            // 0..127
    const int lo = g * SLICE;
    for (int b = j0; b < ABLK; b += 128) {
        int c = bcnt[b * 8 + g];
        const unsigned* seg = bins + ((size_t)b * 8 + g) * BINCAP;
        for (int i = threadIdx.x; i < c; i += 256) {
            unsigned v = seg[i];
            int d = lo + (int)(v >> 17);
            int s = (int)(v & 0x1FFFFu);
            int rk = atomicAdd(&deg[d], 1);
            if (rk < CAP) csrB[(size_t)d * CAP + rk] = s;
        }
    }
}

// gather (bf16 rows in AND out): u[i] = x[i] + sum_nbr x[s]; 8 lanes/node,
// 8 outstanding row-gathers per iteration (vectorized index loads).
__global__ __launch_bounds__(256) void k_agg8(const uint4* __restrict__ xb, uint4* __restrict__ u,
                                              const int* __restrict__ deg, const int* __restrict__ csrB) {
    int gid = blockIdx.x * 256 + threadIdx.x;
    int node = gid >> 3;
    if (node >= NN) return;
    int c = gid & 7;
    uint4 sv = xb[(size_t)node * 8 + c];
    float a0 = bf_lo(sv.x), a1 = bf_hi(sv.x), a2 = bf_lo(sv.y), a3 = bf_hi(sv.y);
    float a4 = bf_lo(sv.z), a5 = bf_hi(sv.z), a6 = bf_lo(sv.w), a7 = bf_hi(sv.w);
    int cnt = deg[node]; if (cnt > CAP) cnt = CAP;
    const int* row = csrB + (size_t)node * CAP;
#define ACC8(vv) { a0 += bf_lo(vv.x); a1 += bf_hi(vv.x); a2 += bf_lo(vv.y); a3 += bf_hi(vv.y); \
                   a4 += bf_lo(vv.z); a5 += bf_hi(vv.z); a6 += bf_lo(vv.w); a7 += bf_hi(vv.w); }
    int e = 0;
    for (; e + 8 <= cnt; e += 8) {
        uint4 i0 = *(const uint4*)&row[e];
        uint4 i1 = *(const uint4*)&row[e + 4];
        uint4 v0 = xb[(size_t)i0.x * 8 + c];
        uint4 v1 = xb[(size_t)i0.y * 8 + c];
        uint4 v2 = xb[(size_t)i0.z * 8 + c];
        uint4 v3 = xb[(size_t)i0.w * 8 + c];
        uint4 v4 = xb[(size_t)i1.x * 8 + c];
        uint4 v5 = xb[(size_t)i1.y * 8 + c];
        uint4 v6 = xb[(size_t)i1.z * 8 + c];
        uint4 v7 = xb[(size_t)i1.w * 8 + c];
        ACC8(v0) ACC8(v1) ACC8(v2) ACC8(v3) ACC8(v4) ACC8(v5) ACC8(v6) ACC8(v7)
    }
    for (; e + 4 <= cnt; e += 4) {
        uint4 i0 = *(const uint4*)&row[e];
        uint4 v0 = xb[(size_t)i0.x * 8 + c];
        uint4 v1 = xb[(size_t)i0.y * 8 + c];
        uint4 v2 = xb[(size_t)i0.z * 8 + c];
        uint4 v3 = xb[(size_t)i0.w * 8 + c];
        ACC8(v0) ACC8(v1) ACC8(v2) ACC8(v3)
    }
    for (; e < cnt; ++e) {
        uint4 v = xb[(size_t)row[e] * 8 + c];
        ACC8(v)
    }
#undef ACC8
    uint4 o;
    o.x = bpack(a0, a1); o.y = bpack(a2, a3); o.z = bpack(a4, a5); o.w = bpack(a6, a7);
    u[(size_t)node * 8 + c] = o;
}

// Pre-pack weights into MFMA B-frag layout (bf16, BN folded into W1/b1).
__global__ __launch_bounds__(256) void k_wprep(const float* __restrict__ W1, const float* __restrict__ b1,
                                               const float* __restrict__ gamma, const float* __restrict__ beta,
                                               const float* __restrict__ rm, const float* __restrict__ rv,
                                               const float* __restrict__ W2, const float* __restrict__ b2,
                                               unsigned* __restrict__ wf, float* __restrict__ bias) {
    int t = threadIdx.x;
    __shared__ float ssc[64];
    if (t < 64) {
        float sc = gamma[t] * rsqrtf(rv[t] + BN_EPS);
        ssc[t] = sc;
        bias[t] = (b1[t] - rm[t]) * sc + beta[t];
        bias[64 + t] = b2[t];
    }
    __syncthreads();
    for (int i = 0; i < 16; ++i) {
        int idx = t + 256 * i;           // 0..4095
        int wp = idx & 3;
        int l  = (idx >> 2) & 63;
        int th = (idx >> 8) & 7;         // c*2+h
        int g  = idx >> 11;
        int h  = th & 1;
        int col = (th >> 1) * 16 + (l & 15);
        int k0 = h * 32 + (l >> 4) * 8 + 2 * wp;
        float w0, w1;
        if (g == 0) { w0 = W1[k0 * 64 + col] * ssc[col]; w1 = W1[(k0 + 1) * 64 + col] * ssc[col]; }
        else        { w0 = W2[k0 * 64 + col];            w1 = W2[(k0 + 1) * 64 + col]; }
        wf[idx] = bpack(w0, w1);
    }
}

// MFMA MLP + pool (m89-verified fragment family; unchanged from round 11)
__global__ __launch_bounds__(256) void k_mlp(const uint4* __restrict__ ub, uint4* __restrict__ hout,
                                             const int* __restrict__ batch, float* __restrict__ p, int layer,
                                             const unsigned* __restrict__ wf, const float* __restrict__ bias) {
    __shared__ unsigned sBF[4096];                   // 16 KB: B-frags, both GEMMs
    __shared__ __align__(16) char sMix[64 * 68 * 4]; // 17.4 KB: sTb (bf16) then sOut (fp32)
    __shared__ float sb1[64], sb2[64];
    __shared__ int sbatch[64];
    const int t = threadIdx.x;
    const int base = blockIdx.x * 64;
    const int w = t >> 6, l = t & 63;

    {
        const uint4* wf4 = (const uint4*)wf;
        uint4* s4 = (uint4*)sBF;
        for (int i = t; i < 1024; i += 256) s4[i] = wf4[i];
    }
    if (t < 64) {
        sb1[t] = bias[t];
        sb2[t] = bias[64 + t];
        int row = base + t;
        sbatch[t] = (row < NN) ? batch[row] : -1;
    }
    int rowg = base + 16 * w + (l & 15);
    if (rowg > NN - 1) rowg = NN - 1;
    uint4 a1u = ub[(size_t)rowg * 8 + (l >> 4)];
    uint4 a2u = ub[(size_t)rowg * 8 + 4 + (l >> 4)];
    bf16x8 a1 = *(bf16x8*)&a1u, a2 = *(bf16x8*)&a2u;
    __syncthreads();

    short* sTb = (short*)sMix;                       // [64][72] bf16
#pragma unroll
    for (int c = 0; c < 4; ++c) {
        f32x4 acc = {0.f, 0.f, 0.f, 0.f};
        uint4 b0u = *(uint4*)&sBF[((c * 2 + 0) * 64 + l) * 4];
        uint4 b1u = *(uint4*)&sBF[((c * 2 + 1) * 64 + l) * 4];
        acc = __builtin_amdgcn_mfma_f32_16x16x32_bf16(a1, *(bf16x8*)&b0u, acc, 0, 0, 0);
        acc = __builtin_amdgcn_mfma_f32_16x16x32_bf16(a2, *(bf16x8*)&b1u, acc, 0, 0, 0);
        int col = c * 16 + (l & 15);
        float bb = sb1[col];
#pragma unroll
        for (int r = 0; r < 4; ++r) {
            int m = 16 * w + (l >> 4) * 4 + r;
            sTb[m * 72 + col] = bf1(fmaxf(acc[r] + bb, 0.f));
        }
    }
    __syncthreads();
    int mrow = 16 * w + (l & 15);
    uint4 t1u = *(uint4*)&sTb[mrow * 72 + (l >> 4) * 8];
    uint4 t2u = *(uint4*)&sTb[mrow * 72 + 32 + (l >> 4) * 8];
    bf16x8 ta1 = *(bf16x8*)&t1u, ta2 = *(bf16x8*)&t2u;
    __syncthreads();
    float (*sOut)[68] = (float(*)[68])sMix;
#pragma unroll
    for (int c = 0; c < 4; ++c) {
        f32x4 acc = {0.f, 0.f, 0.f, 0.f};
        uint4 b0u = *(uint4*)&sBF[2048 + ((c * 2 + 0) * 64 + l) * 4];
        uint4 b1u = *(uint4*)&sBF[2048 + ((c * 2 + 1) * 64 + l) * 4];
        acc = __builtin_amdgcn_mfma_f32_16x16x32_bf16(ta1, *(bf16x8*)&b0u, acc, 0, 0, 0);
        acc = __builtin_amdgcn_mfma_f32_16x16x32_bf16(ta2, *(bf16x8*)&b1u, acc, 0, 0, 0);
        int col = c * 16 + (l & 15);
        float bb = sb2[col];
#pragma unroll
        for (int r = 0; r < 4; ++r)
            sOut[16 * w + (l >> 4) * 4 + r][col] = fmaxf(acc[r] + bb, 0.f);
    }
    __syncthreads();
    {
        int row = t >> 2, q = t & 3;
        int grow = base + row;
        if (grow < NN) {
            const float* sp = &sOut[row][q * 16];
            uint4 o1, o2;
            o1.x = bpack(sp[0], sp[1]);  o1.y = bpack(sp[2], sp[3]);
            o1.z = bpack(sp[4], sp[5]);  o1.w = bpack(sp[6], sp[7]);
            o2.x = bpack(sp[8], sp[9]);  o2.y = bpack(sp[10], sp[11]);
            o2.z = bpack(sp[12], sp[13]); o2.w = bpack(sp[14], sp[15]);
            hout[(size_t)grow * 8 + 2 * q]     = o1;
            hout[(size_t)grow * 8 + 2 * q + 1] = o2;
        }
    }
    if (t < 64) {
        const int j = t;
        float pa = 0.f;
        int gprev = -1;
        for (int r = 0; r < 64; ++r) {
            int row = base + r;
            if (row >= NN) break;
            int g = sbatch[r];
            if (g != gprev) {
                if (gprev >= 0) atomicAdd(&p[gprev * 192 + layer * 64 + j], pa);
                pa = 0.f; gprev = g;
            }
            pa += sOut[r][j];
        }
        if (gprev >= 0) atomicAdd(&p[gprev * 192 + layer * 64 + j], pa);
    }
}

__global__ __launch_bounds__(192) void k_final(const float* __restrict__ p,
                                               const float* __restrict__ W1, const float* __restrict__ b1,
                                               const float* __restrict__ W2, const float* __restrict__ b2,
                                               float* __restrict__ out) {
    int g = blockIdx.x, t = threadIdx.x;
    __shared__ float hg[192];
    __shared__ float y1[192];
    __shared__ float y2[2];
    hg[t] = p[g * 192 + t];
    __syncthreads();
    float acc = b1[t];
    for (int k = 0; k < 192; ++k) acc = fmaf(hg[k], W1[k * 192 + t], acc);
    y1[t] = fmaxf(acc, 0.f);
    __syncthreads();
    if (t < 2) {
        float a = b2[t];
        for (int k = 0; k < 192; ++k) a = fmaf(y1[k], W2[k * 2 + t], a);
        y2[t] = a;
    }
    __syncthreads();
    if (t < 2) {
        float m = fmaxf(y2[0], y2[1]);
        float s = expf(y2[0] - m) + expf(y2[1] - m);
        out[g * 2 + t] = y2[t];
        out[NG * 2 + g * 2 + t] = expf(y2[t] - m) / s;
    }
}

extern "C" void kernel_launch(void* const* d_in, const int* in_sizes, int n_in,
                              void* d_out, int out_size, void* d_ws, size_t ws_size,
                              hipStream_t stream) {
    const float* x    = (const float*)d_in[0];
    const int* ei     = (const int*)d_in[1];
    const int* batch  = (const int*)d_in[2];
    const int* src    = ei;
    const int* dst    = ei + NE;
    const float* lin1_W = (const float*)d_in[27];
    const float* lin1_b = (const float*)d_in[28];
    const float* lin2_W = (const float*)d_in[29];
    const float* lin2_b = (const float*)d_in[30];

    // ws layout (total <= 71,193,216 B, bound proven available rounds 3-11):
    char* w = (char*)d_ws;
    int*   deg  = (int*)w;                                   //   400,000
    float* p    = (float*)(w + 400000);                      //   393,216
    char*  u    = w + 793216;                                // 12,800,000 bf16 [NN][64]
    unsigned* wf  = (unsigned*)(w + 13600000);               //    16,384
    float*    bias= (float*)(w + 13616384);                  //       512
    unsigned* bins= (unsigned*)(w + 13700000);               // 8,388,608 [ABLK][8][BINCAP]
    int*      bcnt= (int*)(w + 22100000);                    //    32,768
    char*  xbhB = w + 26393216;                              // 12,800,000 bf16: x_bf, later hB
    char*  hA   = w + 39193216;                              // 12,800,000 bf16
    int*   csrB = (int*)(w + 51993216);                      // 19,200,000 [NN][CAP]

    // zero deg + p (contiguous)
    k_zero_int<<<(198304 + 255) / 256, 256, 0, stream>>>(deg, 198304);
    // x -> bf16
    k_cvt<<<(NN * 8 + 255) / 256, 256, 0, stream>>>((const float4*)x, (uint4*)xbhB, NN * 8);
    // two-pass CSR build: private LDS binning, then XCD-affine drain
    k_binA<<<ABLK, 256, 0, stream>>>(src, dst, bins, bcnt, deg, csrB);
    k_binB<<<8 * 128, 256, 0, stream>>>(bins, bcnt, deg, csrB);

    const uint4* gin[3]  = { (const uint4*)xbhB, (const uint4*)hA, (const uint4*)xbhB };
    uint4*       gout[3] = { (uint4*)hA,         (uint4*)xbhB,     (uint4*)hA };
    for (int l = 0; l < 3; ++l) {
        const float* W1 = (const float*)d_in[3 + 8 * l + 0];
        const float* b1 = (const float*)d_in[3 + 8 * l + 1];
        const float* ga = (const float*)d_in[3 + 8 * l + 2];
        const float* be = (const float*)d_in[3 + 8 * l + 3];
        const float* rm = (const float*)d_in[3 + 8 * l + 4];
        const float* rv = (const float*)d_in[3 + 8 * l + 5];
        const float* W2 = (const float*)d_in[3 + 8 * l + 6];
        const float* b2 = (const float*)d_in[3 + 8 * l + 7];

        k_wprep<<<1, 256, 0, stream>>>(W1, b1, ga, be, rm, rv, W2, b2, wf, bias);
        k_agg8<<<(NN * 8 + 255) / 256, 256, 0, stream>>>(gin[l], (uint4*)u, deg, csrB);
        k_mlp<<<(NN + 63) / 64, 256, 0, stream>>>((const uint4*)u, gout[l], batch, p, l, wf, bias);
    }
    k_final<<<NG, 192, 0, stream>>>(p, lin1_W, lin1_b, lin2_W, lin2_b, (float*)d_out);
}

// Round 13
// 230.060 us; speedup vs baseline: 1.5033x; 1.0652x over previous
//
#include <hip/hip_runtime.h>

#define NN 100000
#define NE 1200000
#define HD 64
#define NG 512
#define BN_EPS 1e-5f
#define SLICE 12500     // NN/8 dst-nodes per shard
#define ABLK 1024       // pass-A blocks
#define ACHUNK 1172     // ceil(NE/ABLK)
#define BINCAP 256      // per-(Ablock,shard) capacity; mean 146.5, +9 sigma
#define BBLK 16         // pass-B blocks per shard
#define NSUB 98         // 128-node sub-bins per shard (ceil(12500/128))
#define SUBCAP 192      // per-(Bblock,sub) capacity; mean 96, +9.8 sigma
#define NCAP 40         // per-node list cap; P(Poisson(12)>=40) ~ 1e-10

typedef short bf16x8 __attribute__((ext_vector_type(8)));
typedef float f32x4  __attribute__((ext_vector_type(4)));

__device__ __forceinline__ float bf_lo(unsigned v) { return __uint_as_float(v << 16); }
__device__ __forceinline__ float bf_hi(unsigned v) { return __uint_as_float(v & 0xffff0000u); }
__device__ __forceinline__ unsigned bpack(float a, float b) {
    unsigned ua = __float_as_uint(a), ub = __float_as_uint(b);
    ua = (ua + 0x7fffu + ((ua >> 16) & 1u)) >> 16;
    ub = (ub + 0x7fffu + ((ub >> 16) & 1u)) >> 16;
    return ua | (ub << 16);
}
__device__ __forceinline__ short bf1(float a) {
    unsigned ua = __float_as_uint(a);
    return (short)((ua + 0x7fffu + ((ua >> 16) & 1u)) >> 16);
}

__global__ __launch_bounds__(256) void k_zero_int(int* __restrict__ a, int n) {
    int i = blockIdx.x * 256 + threadIdx.x;
    if (i < n) a[i] = 0;
}

__global__ __launch_bounds__(256) void k_cvt(const float4* __restrict__ xf, uint4* __restrict__ xb, int n4) {
    int i = blockIdx.x * 256 + threadIdx.x;
    if (i < n4) {
        float4 f0 = xf[2 * i], f1 = xf[2 * i + 1];
        uint4 o;
        o.x = bpack(f0.x, f0.y); o.y = bpack(f0.z, f0.w);
        o.z = bpack(f1.x, f1.y); o.w = bpack(f1.z, f1.w);
        xb[i] = o;
    }
}

// Pass A: private LDS binning by shard; sequential segment writes; no global atomics.
// pack = (d_local << 17) | src   (d_local < 12500 < 2^14, src < 2^17)
__global__ __launch_bounds__(256) void k_binA(const int* __restrict__ src, const int* __restrict__ dst,
                                              unsigned* __restrict__ bins, int* __restrict__ bcnt) {
    __shared__ unsigned sb[8][BINCAP];
    __shared__ int scnt[8];
    const int b = blockIdx.x, t = threadIdx.x;
    if (t < 8) scnt[t] = 0;
    __syncthreads();
    const int e0 = b * ACHUNK;
    int e1 = e0 + ACHUNK; if (e1 > NE) e1 = NE;
    for (int e = e0 + t; e < e1; e += 256) {
        int d = dst[e], s = src[e];
        int g = d / SLICE;
        int pos = atomicAdd(&scnt[g], 1);
        if (pos < BINCAP) sb[g][pos] = ((unsigned)(d - g * SLICE) << 17) | (unsigned)s;
    }
    __syncthreads();
    for (int i = t; i < 8 * BINCAP; i += 256) {
        int g = i >> 8, pos = i & (BINCAP - 1);
        int c = scnt[g]; if (c > BINCAP) c = BINCAP;
        if (pos < c) bins[((size_t)b * 8 + g) * BINCAP + pos] = sb[g][pos];
    }
    if (t < 8) {
        int c = scnt[t]; if (c > BINCAP) c = BINCAP;
        bcnt[b * 8 + t] = c;
    }
}

// Pass B: 16 blocks per shard re-bin into 98 sub-bins of 128 nodes (LDS cursors,
// private output segments, sequential writes). pack2 = (d7<<17)|src, d7 in [0,128).
__global__ __launch_bounds__(256) void k_binB2(const unsigned* __restrict__ bins, const int* __restrict__ bcnt,
                                               unsigned* __restrict__ bins2, int* __restrict__ bcnt2) {
    __shared__ int cur[NSUB];
    const int g = blockIdx.x >> 4;            // shard 0..7
    const int j = blockIdx.x & 15;            // 0..15
    const int t = threadIdx.x;
    for (int i = t; i < NSUB; i += 256) cur[i] = 0;
    __syncthreads();
    const size_t obase = ((size_t)(g * BBLK + j) * NSUB) * SUBCAP;
    for (int b = j; b < ABLK; b += BBLK) {
        int c = bcnt[b * 8 + g];
        const unsigned* seg = bins + ((size_t)b * 8 + g) * BINCAP;
        for (int i = t; i < c; i += 256) {
            unsigned v = seg[i];
            int dl = (int)(v >> 17);
            int sub = dl >> 7;
            int pos = atomicAdd(&cur[sub], 1);
            if (pos < SUBCAP)
                bins2[obase + (size_t)sub * SUBCAP + pos] = ((unsigned)(dl & 127) << 17) | (v & 0x1FFFFu);
        }
    }
    __syncthreads();
    for (int i = t; i < NSUB; i += 256) {
        int c = cur[i]; if (c > SUBCAP) c = SUBCAP;
        bcnt2[(g * BBLK + j) * NSUB + i] = c;
    }
}

// Pass C: one block per 128-node sub-bin; per-node lists in LDS, then fully
// coalesced sequential writes of csr40 + deg. No global atomics anywhere.
__global__ __launch_bounds__(256) void k_binC(const unsigned* __restrict__ bins2, const int* __restrict__ bcnt2,
                                              int* __restrict__ deg, int* __restrict__ csr40) {
    __shared__ int lists[128 * NCAP];
    __shared__ int cur[128];
    const int g = blockIdx.x / NSUB;
    const int sub = blockIdx.x % NSUB;
    const int t = threadIdx.x;
    if (t < 128) cur[t] = 0;
    __syncthreads();
    for (int j = 0; j < BBLK; ++j) {
        int c = bcnt2[(g * BBLK + j) * NSUB + sub];
        const unsigned* seg = bins2 + ((size_t)(g * BBLK + j) * NSUB + sub) * SUBCAP;
        for (int i = t; i < c; i += 256) {
            unsigned v = seg[i];
            int d7 = (int)(v >> 17);
            int pos = atomicAdd(&cur[d7], 1);
            if (pos < NCAP) lists[d7 * NCAP + pos] = (int)(v & 0x1FFFFu);
        }
    }
    __syncthreads();
    const int node_base = g * SLICE + sub * 128;
    int nlim = SLICE - sub * 128; if (nlim > 128) nlim = 128;
    for (int i = t; i < nlim * NCAP; i += 256) csr40[(size_t)node_base * NCAP + i] = lists[i];
    for (int i = t; i < nlim; i += 256) {
        int c = cur[i]; if (c > NCAP) c = NCAP;
        deg[node_base + i] = c;
    }
}

// gather (bf16 rows in AND out): u[i] = x[i] + sum_nbr x[s]; 8 lanes/node
__global__ __launch_bounds__(256) void k_agg8(const uint4* __restrict__ xb, uint4* __restrict__ u,
                                              const int* __restrict__ deg, const int* __restrict__ csr40) {
    int gid = blockIdx.x * 256 + threadIdx.x;
    int node = gid >> 3;
    if (node >= NN) return;
    int c = gid & 7;
    uint4 sv = xb[(size_t)node * 8 + c];
    float a0 = bf_lo(sv.x), a1 = bf_hi(sv.x), a2 = bf_lo(sv.y), a3 = bf_hi(sv.y);
    float a4 = bf_lo(sv.z), a5 = bf_hi(sv.z), a6 = bf_lo(sv.w), a7 = bf_hi(sv.w);
    int cnt = deg[node]; if (cnt > NCAP) cnt = NCAP;
    const int* row = csr40 + (size_t)node * NCAP;
#define ACC8(vv) { a0 += bf_lo(vv.x); a1 += bf_hi(vv.x); a2 += bf_lo(vv.y); a3 += bf_hi(vv.y); \
                   a4 += bf_lo(vv.z); a5 += bf_hi(vv.z); a6 += bf_lo(vv.w); a7 += bf_hi(vv.w); }
    int e = 0;
    for (; e + 8 <= cnt; e += 8) {
        uint4 i0 = *(const uint4*)&row[e];
        uint4 i1 = *(const uint4*)&row[e + 4];
        uint4 v0 = xb[(size_t)i0.x * 8 + c];
        uint4 v1 = xb[(size_t)i0.y * 8 + c];
        uint4 v2 = xb[(size_t)i0.z * 8 + c];
        uint4 v3 = xb[(size_t)i0.w * 8 + c];
        uint4 v4 = xb[(size_t)i1.x * 8 + c];
        uint4 v5 = xb[(size_t)i1.y * 8 + c];
        uint4 v6 = xb[(size_t)i1.z * 8 + c];
        uint4 v7 = xb[(size_t)i1.w * 8 + c];
        ACC8(v0) ACC8(v1) ACC8(v2) ACC8(v3) ACC8(v4) ACC8(v5) ACC8(v6) ACC8(v7)
    }
    for (; e + 4 <= cnt; e += 4) {
        uint4 i0 = *(const uint4*)&row[e];
        uint4 v0 = xb[(size_t)i0.x * 8 + c];
        uint4 v1 = xb[(size_t)i0.y * 8 + c];
        uint4 v2 = xb[(size_t)i0.z * 8 + c];
        uint4 v3 = xb[(size_t)i0.w * 8 + c];
        ACC8(v0) ACC8(v1) ACC8(v2) ACC8(v3)
    }
    for (; e < cnt; ++e) {
        uint4 v = xb[(size_t)row[e] * 8 + c];
        ACC8(v)
    }
#undef ACC8
    uint4 o;
    o.x = bpack(a0, a1); o.y = bpack(a2, a3); o.z = bpack(a4, a5); o.w = bpack(a6, a7);
    u[(size_t)node * 8 + c] = o;
}

// All 3 layers' weights -> MFMA B-frag layout in one launch (block = layer).
struct WP { const float *W1, *b1, *ga, *be, *rm, *rv, *W2, *b2; };
struct WP3 { WP l[3]; };
__global__ __launch_bounds__(256) void k_wprep3(WP3 wp, unsigned* __restrict__ wf3, float* __restrict__ bias3) {
    const int L = blockIdx.x;
    const WP w = wp.l[L];
    unsigned* wf = wf3 + L * 4096;
    float* bias = bias3 + L * 128;
    int t = threadIdx.x;
    __shared__ float ssc[64];
    if (t < 64) {
        float sc = w.ga[t] * rsqrtf(w.rv[t] + BN_EPS);
        ssc[t] = sc;
        bias[t] = (w.b1[t] - w.rm[t]) * sc + w.be[t];
        bias[64 + t] = w.b2[t];
    }
    __syncthreads();
    for (int i = 0; i < 16; ++i) {
        int idx = t + 256 * i;
        int wpi = idx & 3;
        int l  = (idx >> 2) & 63;
        int th = (idx >> 8) & 7;
        int g  = idx >> 11;
        int h  = th & 1;
        int col = (th >> 1) * 16 + (l & 15);
        int k0 = h * 32 + (l >> 4) * 8 + 2 * wpi;
        float w0, w1;
        if (g == 0) { w0 = w.W1[k0 * 64 + col] * ssc[col]; w1 = w.W1[(k0 + 1) * 64 + col] * ssc[col]; }
        else        { w0 = w.W2[k0 * 64 + col];            w1 = w.W2[(k0 + 1) * 64 + col]; }
        wf[idx] = bpack(w0, w1);
    }
}

// MFMA MLP + pool (m89-verified fragment family)
__global__ __launch_bounds__(256) void k_mlp(const uint4* __restrict__ ub, uint4* __restrict__ hout,
                                             const int* __restrict__ batch, float* __restrict__ p, int layer,
                                             const unsigned* __restrict__ wf, const float* __restrict__ bias) {
    __shared__ unsigned sBF[4096];
    __shared__ __align__(16) char sMix[64 * 68 * 4];
    __shared__ float sb1[64], sb2[64];
    __shared__ int sbatch[64];
    const int t = threadIdx.x;
    const int base = blockIdx.x * 64;
    const int w = t >> 6, l = t & 63;

    {
        const uint4* wf4 = (const uint4*)wf;
        uint4* s4 = (uint4*)sBF;
        for (int i = t; i < 1024; i += 256) s4[i] = wf4[i];
    }
    if (t < 64) {
        sb1[t] = bias[t];
        sb2[t] = bias[64 + t];
        int row = base + t;
        sbatch[t] = (row < NN) ? batch[row] : -1;
    }
    int rowg = base + 16 * w + (l & 15);
    if (rowg > NN - 1) rowg = NN - 1;
    uint4 a1u = ub[(size_t)rowg * 8 + (l >> 4)];
    uint4 a2u = ub[(size_t)rowg * 8 + 4 + (l >> 4)];
    bf16x8 a1 = *(bf16x8*)&a1u, a2 = *(bf16x8*)&a2u;
    __syncthreads();

    short* sTb = (short*)sMix;
#pragma unroll
    for (int c = 0; c < 4; ++c) {
        f32x4 acc = {0.f, 0.f, 0.f, 0.f};
        uint4 b0u = *(uint4*)&sBF[((c * 2 + 0) * 64 + l) * 4];
        uint4 b1u = *(uint4*)&sBF[((c * 2 + 1) * 64 + l) * 4];
        acc = __builtin_amdgcn_mfma_f32_16x16x32_bf16(a1, *(bf16x8*)&b0u, acc, 0, 0, 0);
        acc = __builtin_amdgcn_mfma_f32_16x16x32_bf16(a2, *(bf16x8*)&b1u, acc, 0, 0, 0);
        int col = c * 16 + (l & 15);
        float bb = sb1[col];
#pragma unroll
        for (int r = 0; r < 4; ++r) {
            int m = 16 * w + (l >> 4) * 4 + r;
            sTb[m * 72 + col] = bf1(fmaxf(acc[r] + bb, 0.f));
        }
    }
    __syncthreads();
    int mrow = 16 * w + (l & 15);
    uint4 t1u = *(uint4*)&sTb[mrow * 72 + (l >> 4) * 8];
    uint4 t2u = *(uint4*)&sTb[mrow * 72 + 32 + (l >> 4) * 8];
    bf16x8 ta1 = *(bf16x8*)&t1u, ta2 = *(bf16x8*)&t2u;
    __syncthreads();
    float (*sOut)[68] = (float(*)[68])sMix;
#pragma unroll
    for (int c = 0; c < 4; ++c) {
        f32x4 acc = {0.f, 0.f, 0.f, 0.f};
        uint4 b0u = *(uint4*)&sBF[2048 + ((c * 2 + 0) * 64 + l) * 4];
        uint4 b1u = *(uint4*)&sBF[2048 + ((c * 2 + 1) * 64 + l) * 4];
        acc = __builtin_amdgcn_mfma_f32_16x16x32_bf16(ta1, *(bf16x8*)&b0u, acc, 0, 0, 0);
        acc = __builtin_amdgcn_mfma_f32_16x16x32_bf16(ta2, *(bf16x8*)&b1u, acc, 0, 0, 0);
        int col = c * 16 + (l & 15);
        float bb = sb2[col];
#pragma unroll
        for (int r = 0; r < 4; ++r)
            sOut[16 * w + (l >> 4) * 4 + r][col] = fmaxf(acc[r] + bb, 0.f);
    }
    __syncthreads();
    {
        int row = t >> 2, q = t & 3;
        int grow = base + row;
        if (grow < NN) {
            const float* sp = &sOut[row][q * 16];
            uint4 o1, o2;
            o1.x = bpack(sp[0], sp[1]);  o1.y = bpack(sp[2], sp[3]);
            o1.z = bpack(sp[4], sp[5]);  o1.w = bpack(sp[6], sp[7]);
            o2.x = bpack(sp[8], sp[9]);  o2.y = bpack(sp[10], sp[11]);
            o2.z = bpack(sp[12], sp[13]); o2.w = bpack(sp[14], sp[15]);
            hout[(size_t)grow * 8 + 2 * q]     = o1;
            hout[(size_t)grow * 8 + 2 * q + 1] = o2;
        }
    }
    if (t < 64) {
        const int j = t;
        float pa = 0.f;
        int gprev = -1;
        for (int r = 0; r < 64; ++r) {
            int row = base + r;
            if (row >= NN) break;
            int g = sbatch[r];
            if (g != gprev) {
                if (gprev >= 0) atomicAdd(&p[gprev * 192 + layer * 64 + j], pa);
                pa = 0.f; gprev = g;
            }
            pa += sOut[r][j];
        }
        if (gprev >= 0) atomicAdd(&p[gprev * 192 + layer * 64 + j], pa);
    }
}

__global__ __launch_bounds__(192) void k_final(const float* __restrict__ p,
                                               const float* __restrict__ W1, const float* __restrict__ b1,
                                               const float* __restrict__ W2, const float* __restrict__ b2,
                                               float* __restrict__ out) {
    int g = blockIdx.x, t = threadIdx.x;
    __shared__ float hg[192];
    __shared__ float y1[192];
    __shared__ float y2[2];
    hg[t] = p[g * 192 + t];
    __syncthreads();
    float acc = b1[t];
    for (int k = 0; k < 192; ++k) acc = fmaf(hg[k], W1[k * 192 + t], acc);
    y1[t] = fmaxf(acc, 0.f);
    __syncthreads();
    if (t < 2) {
        float a = b2[t];
        for (int k = 0; k < 192; ++k) a = fmaf(y1[k], W2[k * 2 + t], a);
        y2[t] = a;
    }
    __syncthreads();
    if (t < 2) {
        float m = fmaxf(y2[0], y2[1]);
        float s = expf(y2[0] - m) + expf(y2[1] - m);
        out[g * 2 + t] = y2[t];
        out[NG * 2 + g * 2 + t] = expf(y2[t] - m) / s;
    }
}

extern "C" void kernel_launch(void* const* d_in, const int* in_sizes, int n_in,
                              void* d_out, int out_size, void* d_ws, size_t ws_size,
                              hipStream_t stream) {
    const float* x    = (const float*)d_in[0];
    const int* ei     = (const int*)d_in[1];
    const int* batch  = (const int*)d_in[2];
    const int* src    = ei;
    const int* dst    = ei + NE;
    const float* lin1_W = (const float*)d_in[27];
    const float* lin1_b = (const float*)d_in[28];
    const float* lin2_W = (const float*)d_in[29];
    const float* lin2_b = (const float*)d_in[30];

    // ws layout (max offset 67,993,216 <= 71,193,216 proven available):
    char* w = (char*)d_ws;
    int*      deg   = (int*)w;                               //   400,000
    float*    p     = (float*)(w + 400000);                  //   393,216
    char*     u     = w + 793216;                            // 12,800,000 bf16 [NN][64]
    unsigned* bins2 = (unsigned*)(w + 793216);               //  9,633,792 (overlays u; dead after binC)
    int*      bcnt2 = (int*)(w + 10427008);                  //     50,176
    unsigned* wf3   = (unsigned*)(w + 13600000);             //     49,152 (3 layers)
    float*    bias3 = (float*)(w + 13649152);                //      1,536
    unsigned* bins  = (unsigned*)(w + 13700000);             //  8,388,608 [ABLK][8][BINCAP]
    int*      bcnt  = (int*)(w + 22100000);                  //     32,768
    char*     xbhB  = w + 26393216;                          // 12,800,000 bf16: x_bf, later hB
    char*     hA    = w + 39193216;                          // 12,800,000 bf16
    int*      csr40 = (int*)(w + 51993216);                  // 16,000,000 [NN][NCAP]

    // zero p only (deg fully overwritten by binC)
    k_zero_int<<<(NG * 192 + 255) / 256, 256, 0, stream>>>((int*)p, NG * 192);
    // x -> bf16
    k_cvt<<<(NN * 8 + 255) / 256, 256, 0, stream>>>((const float4*)x, (uint4*)xbhB, NN * 8);
    // weights for all 3 layers in one launch
    WP3 wp;
    for (int l = 0; l < 3; ++l) {
        wp.l[l].W1 = (const float*)d_in[3 + 8 * l + 0];
        wp.l[l].b1 = (const float*)d_in[3 + 8 * l + 1];
        wp.l[l].ga = (const float*)d_in[3 + 8 * l + 2];
        wp.l[l].be = (const float*)d_in[3 + 8 * l + 3];
        wp.l[l].rm = (const float*)d_in[3 + 8 * l + 4];
        wp.l[l].rv = (const float*)d_in[3 + 8 * l + 5];
        wp.l[l].W2 = (const float*)d_in[3 + 8 * l + 6];
        wp.l[l].b2 = (const float*)d_in[3 + 8 * l + 7];
    }
    k_wprep3<<<3, 256, 0, stream>>>(wp, wf3, bias3);
    // 3-pass CSR build: no global atomics, sequential global writes only
    k_binA<<<ABLK, 256, 0, stream>>>(src, dst, bins, bcnt);
    k_binB2<<<8 * BBLK, 256, 0, stream>>>(bins, bcnt, bins2, bcnt2);
    k_binC<<<8 * NSUB, 256, 0, stream>>>(bins2, bcnt2, deg, csr40);

    const uint4* gin[3]  = { (const uint4*)xbhB, (const uint4*)hA, (const uint4*)xbhB };
    uint4*       gout[3] = { (uint4*)hA,         (uint4*)xbhB,     (uint4*)hA };
    for (int l = 0; l < 3; ++l) {
        k_agg8<<<(NN * 8 + 255) / 256, 256, 0, stream>>>(gin[l], (uint4*)u, deg, csr40);
        k_mlp<<<(NN + 63) / 64, 256, 0, stream>>>((const uint4*)u, gout[l], batch, p, l,
                                                  wf3 + l * 4096, bias3 + l * 128);
    }
    k_final<<<NG, 192, 0, stream>>>(p, lin1_W, lin1_b, lin2_W, lin2_b, (float*)d_out);
}

// Round 14
// 219.945 us; speedup vs baseline: 1.5724x; 1.0460x over previous
//
#include <hip/hip_runtime.h>

#define NN 100000
#define NE 1200000
#define HD 64
#define NG 512
#define BN_EPS 1e-5f
#define SLICE 12500     // NN/8 dst-nodes per shard
#define ABLK 1024       // pass-A blocks
#define ACHUNK 1172     // ceil(NE/ABLK)
#define BINCAP 256      // per-(Ablock,shard) capacity; mean 146.5, +9 sigma
#define BBLK 32         // pass-B blocks per shard (256 total)
#define NSUB 98         // 128-node sub-bins per shard
#define SUBCAP 96       // per-(Bblock,sub) capacity; mean 47.8, +7 sigma
#define NCAP 40         // per-node list cap; P(Poisson(12)>=40) ~ 1e-10

typedef short bf16x8 __attribute__((ext_vector_type(8)));
typedef float f32x4  __attribute__((ext_vector_type(4)));

__device__ __forceinline__ float bf_lo(unsigned v) { return __uint_as_float(v << 16); }
__device__ __forceinline__ float bf_hi(unsigned v) { return __uint_as_float(v & 0xffff0000u); }
__device__ __forceinline__ unsigned bpack(float a, float b) {
    unsigned ua = __float_as_uint(a), ub = __float_as_uint(b);
    ua = (ua + 0x7fffu + ((ua >> 16) & 1u)) >> 16;
    ub = (ub + 0x7fffu + ((ub >> 16) & 1u)) >> 16;
    return ua | (ub << 16);
}
__device__ __forceinline__ short bf1(float a) {
    unsigned ua = __float_as_uint(a);
    return (short)((ua + 0x7fffu + ((ua >> 16) & 1u)) >> 16);
}

__global__ __launch_bounds__(256) void k_zero_int(int* __restrict__ a, int n) {
    int i = blockIdx.x * 256 + threadIdx.x;
    if (i < n) a[i] = 0;
}

__global__ __launch_bounds__(256) void k_cvt(const float4* __restrict__ xf, uint4* __restrict__ xb, int n4) {
    int i = blockIdx.x * 256 + threadIdx.x;
    if (i < n4) {
        float4 f0 = xf[2 * i], f1 = xf[2 * i + 1];
        uint4 o;
        o.x = bpack(f0.x, f0.y); o.y = bpack(f0.z, f0.w);
        o.z = bpack(f1.x, f1.y); o.w = bpack(f1.z, f1.w);
        xb[i] = o;
    }
}

// Pass A: private LDS binning by shard; sequential segment writes; no global atomics.
// pack = (d_local << 17) | src
__global__ __launch_bounds__(256) void k_binA(const int* __restrict__ src, const int* __restrict__ dst,
                                              unsigned* __restrict__ bins, int* __restrict__ bcnt) {
    __shared__ unsigned sb[8][BINCAP];
    __shared__ int scnt[8];
    const int b = blockIdx.x, t = threadIdx.x;
    if (t < 8) scnt[t] = 0;
    __syncthreads();
    const int e0 = b * ACHUNK;
    int e1 = e0 + ACHUNK; if (e1 > NE) e1 = NE;
    for (int e = e0 + t; e < e1; e += 256) {
        int d = dst[e], s = src[e];
        int g = d / SLICE;
        int pos = atomicAdd(&scnt[g], 1);
        if (pos < BINCAP) sb[g][pos] = ((unsigned)(d - g * SLICE) << 17) | (unsigned)s;
    }
    __syncthreads();
    for (int i = t; i < 8 * BINCAP; i += 256) {
        int g = i >> 8, pos = i & (BINCAP - 1);
        int c = scnt[g]; if (c > BINCAP) c = BINCAP;
        if (pos < c) bins[((size_t)b * 8 + g) * BINCAP + pos] = sb[g][pos];
    }
    if (t < 8) {
        int c = scnt[t]; if (c > BINCAP) c = BINCAP;
        bcnt[b * 8 + t] = c;
    }
}

// Pass B: 32 blocks per shard re-bin into 98 sub-bins of 128 nodes (LDS cursors,
// private output segments, sequential writes).
__global__ __launch_bounds__(256) void k_binB2(const unsigned* __restrict__ bins, const int* __restrict__ bcnt,
                                               unsigned* __restrict__ bins2, int* __restrict__ bcnt2) {
    __shared__ int cur[NSUB];
    const int g = blockIdx.x / BBLK;
    const int j = blockIdx.x % BBLK;
    const int t = threadIdx.x;
    for (int i = t; i < NSUB; i += 256) cur[i] = 0;
    __syncthreads();
    const size_t obase = ((size_t)(g * BBLK + j) * NSUB) * SUBCAP;
    for (int b = j; b < ABLK; b += BBLK) {
        int c = bcnt[b * 8 + g];
        const unsigned* seg = bins + ((size_t)b * 8 + g) * BINCAP;
        for (int i = t; i < c; i += 256) {
            unsigned v = seg[i];
            int dl = (int)(v >> 17);
            int sub = dl >> 7;
            int pos = atomicAdd(&cur[sub], 1);
            if (pos < SUBCAP)
                bins2[obase + (size_t)sub * SUBCAP + pos] = ((unsigned)(dl & 127) << 17) | (v & 0x1FFFFu);
        }
    }
    __syncthreads();
    for (int i = t; i < NSUB; i += 256) {
        int c = cur[i]; if (c > SUBCAP) c = SUBCAP;
        bcnt2[(g * BBLK + j) * NSUB + i] = c;
    }
}

// Pass C: one block per 128-node sub-bin; per-node lists in LDS, coalesced
// sequential writes of csr40 + deg. Counts prefetched to LDS.
__global__ __launch_bounds__(256) void k_binC(const unsigned* __restrict__ bins2, const int* __restrict__ bcnt2,
                                              int* __restrict__ deg, int* __restrict__ csr40) {
    __shared__ int lists[128 * NCAP];
    __shared__ int cur[128];
    __shared__ int jc[BBLK];
    const int g = blockIdx.x / NSUB;
    const int sub = blockIdx.x % NSUB;
    const int t = threadIdx.x;
    if (t < 128) cur[t] = 0;
    if (t < BBLK) jc[t] = bcnt2[(g * BBLK + t) * NSUB + sub];
    __syncthreads();
    for (int j = 0; j < BBLK; ++j) {
        int c = jc[j];
        const unsigned* seg = bins2 + ((size_t)(g * BBLK + j) * NSUB + sub) * SUBCAP;
        for (int i = t; i < c; i += 256) {
            unsigned v = seg[i];
            int d7 = (int)(v >> 17);
            int pos = atomicAdd(&cur[d7], 1);
            if (pos < NCAP) lists[d7 * NCAP + pos] = (int)(v & 0x1FFFFu);
        }
    }
    __syncthreads();
    const int node_base = g * SLICE + sub * 128;
    int nlim = SLICE - sub * 128; if (nlim > 128) nlim = 128;
    for (int i = t; i < nlim * NCAP; i += 256) csr40[(size_t)node_base * NCAP + i] = lists[i];
    for (int i = t; i < nlim; i += 256) {
        int c = cur[i]; if (c > NCAP) c = NCAP;
        deg[node_base + i] = c;
    }
}

// All 3 layers' weights -> MFMA B-frag layout in one launch (block = layer).
struct WP { const float *W1, *b1, *ga, *be, *rm, *rv, *W2, *b2; };
struct WP3 { WP l[3]; };
__global__ __launch_bounds__(256) void k_wprep3(WP3 wp, unsigned* __restrict__ wf3, float* __restrict__ bias3) {
    const int L = blockIdx.x;
    const WP w = wp.l[L];
    unsigned* wf = wf3 + L * 4096;
    float* bias = bias3 + L * 128;
    int t = threadIdx.x;
    __shared__ float ssc[64];
    if (t < 64) {
        float sc = w.ga[t] * rsqrtf(w.rv[t] + BN_EPS);
        ssc[t] = sc;
        bias[t] = (w.b1[t] - w.rm[t]) * sc + w.be[t];
        bias[64 + t] = w.b2[t];
    }
    __syncthreads();
    for (int i = 0; i < 16; ++i) {
        int idx = t + 256 * i;
        int wpi = idx & 3;
        int l  = (idx >> 2) & 63;
        int th = (idx >> 8) & 7;
        int g  = idx >> 11;
        int h  = th & 1;
        int col = (th >> 1) * 16 + (l & 15);
        int k0 = h * 32 + (l >> 4) * 8 + 2 * wpi;
        float w0, w1;
        if (g == 0) { w0 = w.W1[k0 * 64 + col] * ssc[col]; w1 = w.W1[(k0 + 1) * 64 + col] * ssc[col]; }
        else        { w0 = w.W2[k0 * 64 + col];            w1 = w.W2[(k0 + 1) * 64 + col]; }
        wf[idx] = bpack(w0, w1);
    }
}

// Fused layer: inline gather (registers only) + MFMA MLP + h write + pool.
// Thread (w,l) owns row 16w+(l&15), chunks c1=l>>4 and c2=4+(l>>4) — exactly
// its GEMM1 A-fragments. Gather: 4-neighbor unroll, 8 loads in flight.
__global__ __launch_bounds__(256) void k_layer(const uint4* __restrict__ gin, uint4* __restrict__ hout,
                                               const int* __restrict__ deg, const int* __restrict__ csr40,
                                               const int* __restrict__ batch, float* __restrict__ p, int layer,
                                               const unsigned* __restrict__ wf, const float* __restrict__ bias) {
    __shared__ unsigned sBF[4096];                   // 16 KB B-frags (both GEMMs)
    __shared__ __align__(16) char sMix[64 * 68 * 4]; // 17.4 KB: sTb bf16, then sOut fp32
    __shared__ float sb1[64], sb2[64];
    __shared__ int sbatch[64];
    const int t = threadIdx.x;
    const int base = blockIdx.x * 64;
    const int w = t >> 6, l = t & 63;

    {   // issue B-frag staging first; fills under gather latency
        const uint4* wf4 = (const uint4*)wf;
        uint4* s4 = (uint4*)sBF;
        for (int i = t; i < 1024; i += 256) s4[i] = wf4[i];
    }
    if (t < 64) {
        sb1[t] = bias[t];
        sb2[t] = bias[64 + t];
        int row = base + t;
        sbatch[t] = (row < NN) ? batch[row] : -1;
    }

    // ---- inline gather into registers ----
    int rowg = base + 16 * w + (l & 15);
    if (rowg > NN - 1) rowg = NN - 1;
    const int c1 = l >> 4, c2 = 4 + (l >> 4);
    uint4 s1 = gin[(size_t)rowg * 8 + c1];
    uint4 s2 = gin[(size_t)rowg * 8 + c2];
    float g0 = bf_lo(s1.x), g1 = bf_hi(s1.x), g2 = bf_lo(s1.y), g3 = bf_hi(s1.y);
    float g4 = bf_lo(s1.z), g5 = bf_hi(s1.z), g6 = bf_lo(s1.w), g7 = bf_hi(s1.w);
    float h0 = bf_lo(s2.x), h1 = bf_hi(s2.x), h2 = bf_lo(s2.y), h3 = bf_hi(s2.y);
    float h4 = bf_lo(s2.z), h5 = bf_hi(s2.z), h6 = bf_lo(s2.w), h7 = bf_hi(s2.w);
    int cnt = deg[rowg]; if (cnt > NCAP) cnt = NCAP;
    const int* rw = csr40 + (size_t)rowg * NCAP;
#define ACCG(vv) { g0 += bf_lo(vv.x); g1 += bf_hi(vv.x); g2 += bf_lo(vv.y); g3 += bf_hi(vv.y); \
                   g4 += bf_lo(vv.z); g5 += bf_hi(vv.z); g6 += bf_lo(vv.w); g7 += bf_hi(vv.w); }
#define ACCH(vv) { h0 += bf_lo(vv.x); h1 += bf_hi(vv.x); h2 += bf_lo(vv.y); h3 += bf_hi(vv.y); \
                   h4 += bf_lo(vv.z); h5 += bf_hi(vv.z); h6 += bf_lo(vv.w); h7 += bf_hi(vv.w); }
    int e = 0;
    for (; e + 4 <= cnt; e += 4) {
        uint4 ix = *(const uint4*)&rw[e];
        uint4 va = gin[(size_t)ix.x * 8 + c1];
        uint4 vb = gin[(size_t)ix.x * 8 + c2];
        uint4 vc = gin[(size_t)ix.y * 8 + c1];
        uint4 vd = gin[(size_t)ix.y * 8 + c2];
        uint4 ve = gin[(size_t)ix.z * 8 + c1];
        uint4 vf = gin[(size_t)ix.z * 8 + c2];
        uint4 vg = gin[(size_t)ix.w * 8 + c1];
        uint4 vh = gin[(size_t)ix.w * 8 + c2];
        ACCG(va) ACCH(vb) ACCG(vc) ACCH(vd) ACCG(ve) ACCH(vf) ACCG(vg) ACCH(vh)
    }
    for (; e < cnt; ++e) {
        int ix = rw[e];
        uint4 va = gin[(size_t)ix * 8 + c1];
        uint4 vb = gin[(size_t)ix * 8 + c2];
        ACCG(va) ACCH(vb)
    }
#undef ACCG
#undef ACCH
    uint4 a1u, a2u;
    a1u.x = bpack(g0, g1); a1u.y = bpack(g2, g3); a1u.z = bpack(g4, g5); a1u.w = bpack(g6, g7);
    a2u.x = bpack(h0, h1); a2u.y = bpack(h2, h3); a2u.z = bpack(h4, h5); a2u.w = bpack(h6, h7);
    bf16x8 a1 = *(bf16x8*)&a1u, a2 = *(bf16x8*)&a2u;
    __syncthreads();   // sBF staged

    short* sTb = (short*)sMix;                       // [64][72] bf16
#pragma unroll
    for (int c = 0; c < 4; ++c) {
        f32x4 acc = {0.f, 0.f, 0.f, 0.f};
        uint4 b0u = *(uint4*)&sBF[((c * 2 + 0) * 64 + l) * 4];
        uint4 b1u = *(uint4*)&sBF[((c * 2 + 1) * 64 + l) * 4];
        acc = __builtin_amdgcn_mfma_f32_16x16x32_bf16(a1, *(bf16x8*)&b0u, acc, 0, 0, 0);
        acc = __builtin_amdgcn_mfma_f32_16x16x32_bf16(a2, *(bf16x8*)&b1u, acc, 0, 0, 0);
        int col = c * 16 + (l & 15);
        float bb = sb1[col];
#pragma unroll
        for (int r = 0; r < 4; ++r) {
            int m = 16 * w + (l >> 4) * 4 + r;
            sTb[m * 72 + col] = bf1(fmaxf(acc[r] + bb, 0.f));
        }
    }
    __syncthreads();
    int mrow = 16 * w + (l & 15);
    uint4 t1u = *(uint4*)&sTb[mrow * 72 + (l >> 4) * 8];
    uint4 t2u = *(uint4*)&sTb[mrow * 72 + 32 + (l >> 4) * 8];
    bf16x8 ta1 = *(bf16x8*)&t1u, ta2 = *(bf16x8*)&t2u;
    __syncthreads();
    float (*sOut)[68] = (float(*)[68])sMix;
#pragma unroll
    for (int c = 0; c < 4; ++c) {
        f32x4 acc = {0.f, 0.f, 0.f, 0.f};
        uint4 b0u = *(uint4*)&sBF[2048 + ((c * 2 + 0) * 64 + l) * 4];
        uint4 b1u = *(uint4*)&sBF[2048 + ((c * 2 + 1) * 64 + l) * 4];
        acc = __builtin_amdgcn_mfma_f32_16x16x32_bf16(ta1, *(bf16x8*)&b0u, acc, 0, 0, 0);
        acc = __builtin_amdgcn_mfma_f32_16x16x32_bf16(ta2, *(bf16x8*)&b1u, acc, 0, 0, 0);
        int col = c * 16 + (l & 15);
        float bb = sb2[col];
#pragma unroll
        for (int r = 0; r < 4; ++r)
            sOut[16 * w + (l >> 4) * 4 + r][col] = fmaxf(acc[r] + bb, 0.f);
    }
    __syncthreads();
    {
        int row = t >> 2, q = t & 3;
        int grow = base + row;
        if (grow < NN) {
            const float* sp = &sOut[row][q * 16];
            uint4 o1, o2;
            o1.x = bpack(sp[0], sp[1]);  o1.y = bpack(sp[2], sp[3]);
            o1.z = bpack(sp[4], sp[5]);  o1.w = bpack(sp[6], sp[7]);
            o2.x = bpack(sp[8], sp[9]);  o2.y = bpack(sp[10], sp[11]);
            o2.z = bpack(sp[12], sp[13]); o2.w = bpack(sp[14], sp[15]);
            hout[(size_t)grow * 8 + 2 * q]     = o1;
            hout[(size_t)grow * 8 + 2 * q + 1] = o2;
        }
    }
    if (t < 64) {
        const int j = t;
        float pa = 0.f;
        int gprev = -1;
        for (int r = 0; r < 64; ++r) {
            int row = base + r;
            if (row >= NN) break;
            int g = sbatch[r];
            if (g != gprev) {
                if (gprev >= 0) atomicAdd(&p[gprev * 192 + layer * 64 + j], pa);
                pa = 0.f; gprev = g;
            }
            pa += sOut[r][j];
        }
        if (gprev >= 0) atomicAdd(&p[gprev * 192 + layer * 64 + j], pa);
    }
}

__global__ __launch_bounds__(192) void k_final(const float* __restrict__ p,
                                               const float* __restrict__ W1, const float* __restrict__ b1,
                                               const float* __restrict__ W2, const float* __restrict__ b2,
                                               float* __restrict__ out) {
    int g = blockIdx.x, t = threadIdx.x;
    __shared__ float hg[192];
    __shared__ float y1[192];
    __shared__ float y2[2];
    hg[t] = p[g * 192 + t];
    __syncthreads();
    float acc = b1[t];
    for (int k = 0; k < 192; ++k) acc = fmaf(hg[k], W1[k * 192 + t], acc);
    y1[t] = fmaxf(acc, 0.f);
    __syncthreads();
    if (t < 2) {
        float a = b2[t];
        for (int k = 0; k < 192; ++k) a = fmaf(y1[k], W2[k * 2 + t], a);
        y2[t] = a;
    }
    __syncthreads();
    if (t < 2) {
        float m = fmaxf(y2[0], y2[1]);
        float s = expf(y2[0] - m) + expf(y2[1] - m);
        out[g * 2 + t] = y2[t];
        out[NG * 2 + g * 2 + t] = expf(y2[t] - m) / s;
    }
}

extern "C" void kernel_launch(void* const* d_in, const int* in_sizes, int n_in,
                              void* d_out, int out_size, void* d_ws, size_t ws_size,
                              hipStream_t stream) {
    const float* x    = (const float*)d_in[0];
    const int* ei     = (const int*)d_in[1];
    const int* batch  = (const int*)d_in[2];
    const int* src    = ei;
    const int* dst    = ei + NE;
    const float* lin1_W = (const float*)d_in[27];
    const float* lin1_b = (const float*)d_in[28];
    const float* lin2_W = (const float*)d_in[29];
    const float* lin2_b = (const float*)d_in[30];

    // ws layout (max offset 67,993,216 <= 71,193,216 proven available):
    char* w = (char*)d_ws;
    int*      deg   = (int*)w;                               //   400,000
    float*    p     = (float*)(w + 400000);                  //   393,216
    unsigned* bins2 = (unsigned*)(w + 793216);               //  9,633,792
    int*      bcnt2 = (int*)(w + 10427008);                  //    100,352
    unsigned* wf3   = (unsigned*)(w + 13600000);             //     49,152
    float*    bias3 = (float*)(w + 13649152);                //      1,536
    unsigned* bins  = (unsigned*)(w + 13700000);             //  8,388,608
    int*      bcnt  = (int*)(w + 22100000);                  //     32,768
    char*     xbhB  = w + 26393216;                          // 12,800,000 bf16: x_bf, later hB
    char*     hA    = w + 39193216;                          // 12,800,000 bf16
    int*      csr40 = (int*)(w + 51993216);                  // 16,000,000 [NN][NCAP]

    k_zero_int<<<(NG * 192 + 255) / 256, 256, 0, stream>>>((int*)p, NG * 192);
    k_cvt<<<(NN * 8 + 255) / 256, 256, 0, stream>>>((const float4*)x, (uint4*)xbhB, NN * 8);
    WP3 wp;
    for (int l = 0; l < 3; ++l) {
        wp.l[l].W1 = (const float*)d_in[3 + 8 * l + 0];
        wp.l[l].b1 = (const float*)d_in[3 + 8 * l + 1];
        wp.l[l].ga = (const float*)d_in[3 + 8 * l + 2];
        wp.l[l].be = (const float*)d_in[3 + 8 * l + 3];
        wp.l[l].rm = (const float*)d_in[3 + 8 * l + 4];
        wp.l[l].rv = (const float*)d_in[3 + 8 * l + 5];
        wp.l[l].W2 = (const float*)d_in[3 + 8 * l + 6];
        wp.l[l].b2 = (const float*)d_in[3 + 8 * l + 7];
    }
    k_wprep3<<<3, 256, 0, stream>>>(wp, wf3, bias3);
    // 3-pass CSR build: no global atomics, sequential global writes only
    k_binA<<<ABLK, 256, 0, stream>>>(src, dst, bins, bcnt);
    k_binB2<<<8 * BBLK, 256, 0, stream>>>(bins, bcnt, bins2, bcnt2);
    k_binC<<<8 * NSUB, 256, 0, stream>>>(bins2, bcnt2, deg, csr40);

    const uint4* gin[3]  = { (const uint4*)xbhB, (const uint4*)hA, (const uint4*)xbhB };
    uint4*       gout[3] = { (uint4*)hA,         (uint4*)xbhB,     (uint4*)hA };
    for (int l = 0; l < 3; ++l) {
        k_layer<<<(NN + 63) / 64, 256, 0, stream>>>(gin[l], gout[l], deg, csr40, batch, p, l,
                                                    wf3 + l * 4096, bias3 + l * 128);
    }
    k_final<<<NG, 192, 0, stream>>>(p, lin1_W, lin1_b, lin2_W, lin2_b, (float*)d_out);
}

// Round 15
// 183.249 us; speedup vs baseline: 1.8873x; 1.2002x over previous
//
#include <hip/hip_runtime.h>

#define NN 100000
#define NE 1200000
#define HD 64
#define NG 512
#define BN_EPS 1e-5f
#define SLICE 12500     // NN/8 dst-nodes per shard
#define ABLK 1024       // pass-A blocks
#define ACHUNK 1172     // ceil(NE/ABLK)
#define BINCAP 256      // per-(Ablock,shard) capacity; mean 146.5, +9 sigma
#define BBLK 32         // pass-B blocks per shard (256 total)
#define NSUB 98         // 128-node sub-bins per shard
#define SUBCAP 96       // per-(Bblock,sub) capacity; mean 47.8, +7 sigma
#define NCAP 40         // per-node list cap; P(Poisson(12)>=40) ~ 1e-10

typedef short bf16x8 __attribute__((ext_vector_type(8)));
typedef float f32x4  __attribute__((ext_vector_type(4)));

__device__ __forceinline__ float bf_lo(unsigned v) { return __uint_as_float(v << 16); }
__device__ __forceinline__ float bf_hi(unsigned v) { return __uint_as_float(v & 0xffff0000u); }
__device__ __forceinline__ unsigned bpack(float a, float b) {
    unsigned ua = __float_as_uint(a), ub = __float_as_uint(b);
    ua = (ua + 0x7fffu + ((ua >> 16) & 1u)) >> 16;
    ub = (ub + 0x7fffu + ((ub >> 16) & 1u)) >> 16;
    return ua | (ub << 16);
}
__device__ __forceinline__ short bf1(float a) {
    unsigned ua = __float_as_uint(a);
    return (short)((ua + 0x7fffu + ((ua >> 16) & 1u)) >> 16);
}

__global__ __launch_bounds__(256) void k_zero_int(int* __restrict__ a, int n) {
    int i = blockIdx.x * 256 + threadIdx.x;
    if (i < n) a[i] = 0;
}

__global__ __launch_bounds__(256) void k_cvt(const float4* __restrict__ xf, uint4* __restrict__ xb, int n4) {
    int i = blockIdx.x * 256 + threadIdx.x;
    if (i < n4) {
        float4 f0 = xf[2 * i], f1 = xf[2 * i + 1];
        uint4 o;
        o.x = bpack(f0.x, f0.y); o.y = bpack(f0.z, f0.w);
        o.z = bpack(f1.x, f1.y); o.w = bpack(f1.z, f1.w);
        xb[i] = o;
    }
}

// Pass A: private LDS binning by shard; sequential segment writes; no global atomics.
__global__ __launch_bounds__(256) void k_binA(const int* __restrict__ src, const int* __restrict__ dst,
                                              unsigned* __restrict__ bins, int* __restrict__ bcnt) {
    __shared__ unsigned sb[8][BINCAP];
    __shared__ int scnt[8];
    const int b = blockIdx.x, t = threadIdx.x;
    if (t < 8) scnt[t] = 0;
    __syncthreads();
    const int e0 = b * ACHUNK;
    int e1 = e0 + ACHUNK; if (e1 > NE) e1 = NE;
    for (int e = e0 + t; e < e1; e += 256) {
        int d = dst[e], s = src[e];
        int g = d / SLICE;
        int pos = atomicAdd(&scnt[g], 1);
        if (pos < BINCAP) sb[g][pos] = ((unsigned)(d - g * SLICE) << 17) | (unsigned)s;
    }
    __syncthreads();
    for (int i = t; i < 8 * BINCAP; i += 256) {
        int g = i >> 8, pos = i & (BINCAP - 1);
        int c = scnt[g]; if (c > BINCAP) c = BINCAP;
        if (pos < c) bins[((size_t)b * 8 + g) * BINCAP + pos] = sb[g][pos];
    }
    if (t < 8) {
        int c = scnt[t]; if (c > BINCAP) c = BINCAP;
        bcnt[b * 8 + t] = c;
    }
}

// Pass B: 32 blocks per shard re-bin into 98 sub-bins of 128 nodes.
__global__ __launch_bounds__(256) void k_binB2(const unsigned* __restrict__ bins, const int* __restrict__ bcnt,
                                               unsigned* __restrict__ bins2, int* __restrict__ bcnt2) {
    __shared__ int cur[NSUB];
    const int g = blockIdx.x / BBLK;
    const int j = blockIdx.x % BBLK;
    const int t = threadIdx.x;
    for (int i = t; i < NSUB; i += 256) cur[i] = 0;
    __syncthreads();
    const size_t obase = ((size_t)(g * BBLK + j) * NSUB) * SUBCAP;
    for (int b = j; b < ABLK; b += BBLK) {
        int c = bcnt[b * 8 + g];
        const unsigned* seg = bins + ((size_t)b * 8 + g) * BINCAP;
        for (int i = t; i < c; i += 256) {
            unsigned v = seg[i];
            int dl = (int)(v >> 17);
            int sub = dl >> 7;
            int pos = atomicAdd(&cur[sub], 1);
            if (pos < SUBCAP)
                bins2[obase + (size_t)sub * SUBCAP + pos] = ((unsigned)(dl & 127) << 17) | (v & 0x1FFFFu);
        }
    }
    __syncthreads();
    for (int i = t; i < NSUB; i += 256) {
        int c = cur[i]; if (c > SUBCAP) c = SUBCAP;
        bcnt2[(g * BBLK + j) * NSUB + i] = c;
    }
}

// Pass C: one block per 128-node sub-bin; per-node lists in LDS, coalesced writes.
__global__ __launch_bounds__(256) void k_binC(const unsigned* __restrict__ bins2, const int* __restrict__ bcnt2,
                                              int* __restrict__ deg, int* __restrict__ csr40) {
    __shared__ int lists[128 * NCAP];
    __shared__ int cur[128];
    __shared__ int jc[BBLK];
    const int g = blockIdx.x / NSUB;
    const int sub = blockIdx.x % NSUB;
    const int t = threadIdx.x;
    if (t < 128) cur[t] = 0;
    if (t < BBLK) jc[t] = bcnt2[(g * BBLK + t) * NSUB + sub];
    __syncthreads();
    for (int j = 0; j < BBLK; ++j) {
        int c = jc[j];
        const unsigned* seg = bins2 + ((size_t)(g * BBLK + j) * NSUB + sub) * SUBCAP;
        for (int i = t; i < c; i += 256) {
            unsigned v = seg[i];
            int d7 = (int)(v >> 17);
            int pos = atomicAdd(&cur[d7], 1);
            if (pos < NCAP) lists[d7 * NCAP + pos] = (int)(v & 0x1FFFFu);
        }
    }
    __syncthreads();
    const int node_base = g * SLICE + sub * 128;
    int nlim = SLICE - sub * 128; if (nlim > 128) nlim = 128;
    for (int i = t; i < nlim * NCAP; i += 256) csr40[(size_t)node_base * NCAP + i] = lists[i];
    for (int i = t; i < nlim; i += 256) {
        int c = cur[i]; if (c > NCAP) c = NCAP;
        deg[node_base + i] = c;
    }
}

// All 3 layers' weights -> MFMA B-frag layout in one launch (block = layer).
struct WP { const float *W1, *b1, *ga, *be, *rm, *rv, *W2, *b2; };
struct WP3 { WP l[3]; };
__global__ __launch_bounds__(256) void k_wprep3(WP3 wp, unsigned* __restrict__ wf3, float* __restrict__ bias3) {
    const int L = blockIdx.x;
    const WP w = wp.l[L];
    unsigned* wf = wf3 + L * 4096;
    float* bias = bias3 + L * 128;
    int t = threadIdx.x;
    __shared__ float ssc[64];
    if (t < 64) {
        float sc = w.ga[t] * rsqrtf(w.rv[t] + BN_EPS);
        ssc[t] = sc;
        bias[t] = (w.b1[t] - w.rm[t]) * sc + w.be[t];
        bias[64 + t] = w.b2[t];
    }
    __syncthreads();
    for (int i = 0; i < 16; ++i) {
        int idx = t + 256 * i;
        int wpi = idx & 3;
        int l  = (idx >> 2) & 63;
        int th = (idx >> 8) & 7;
        int g  = idx >> 11;
        int h  = th & 1;
        int col = (th >> 1) * 16 + (l & 15);
        int k0 = h * 32 + (l >> 4) * 8 + 2 * wpi;
        float w0, w1;
        if (g == 0) { w0 = w.W1[k0 * 64 + col] * ssc[col]; w1 = w.W1[(k0 + 1) * 64 + col] * ssc[col]; }
        else        { w0 = w.W2[k0 * 64 + col];            w1 = w.W2[(k0 + 1) * 64 + col]; }
        wf[idx] = bpack(w0, w1);
    }
}

// Fused layer: COALESCED gather into LDS (8 lanes/node) + MFMA MLP (B-frags
// straight from L2-resident global wf; no weight LDS) + h write + pool.
// LDS ~18 KB -> 8 blocks/CU.
__global__ __launch_bounds__(256) void k_layer(const uint4* __restrict__ gin, uint4* __restrict__ hout,
                                               const int* __restrict__ deg, const int* __restrict__ csr40,
                                               const int* __restrict__ batch, float* __restrict__ p, int layer,
                                               const uint4* __restrict__ wf4, const float* __restrict__ bias) {
    __shared__ __align__(16) char sMix[64 * 68 * 4]; // 17.4 KB: sU bf16 -> sTb bf16 -> sOut fp32
    __shared__ float sb1[64], sb2[64];
    __shared__ int sbatch[64];
    const int t = threadIdx.x;
    const int base = blockIdx.x * 64;
    const int w = t >> 6, l = t & 63;

    if (t < 64) {
        sb1[t] = bias[t];
        sb2[t] = bias[64 + t];
        int row = base + t;
        sbatch[t] = (row < NN) ? batch[row] : -1;
    }

    // ---- coalesced gather: 8 lanes per node, chunk c = 16B per lane ----
    short* sU = (short*)sMix;                        // [64][72] bf16 (144B row stride)
    {
        const int grp = t >> 3;                      // 0..31
        const int c = t & 7;
#define ACCX(vv) { a0 += bf_lo(vv.x); a1 += bf_hi(vv.x); a2 += bf_lo(vv.y); a3 += bf_hi(vv.y); \
                   a4 += bf_lo(vv.z); a5 += bf_hi(vv.z); a6 += bf_lo(vv.w); a7 += bf_hi(vv.w); }
        for (int rr = grp; rr < 64; rr += 32) {
            int row = base + rr;
            float a0 = 0.f, a1 = 0.f, a2 = 0.f, a3 = 0.f, a4 = 0.f, a5 = 0.f, a6 = 0.f, a7 = 0.f;
            if (row < NN) {
                uint4 sv = gin[(size_t)row * 8 + c];
                ACCX(sv)
                int cnt = deg[row]; if (cnt > NCAP) cnt = NCAP;
                const int* rw = csr40 + (size_t)row * NCAP;
                int e = 0;
                for (; e + 4 <= cnt; e += 4) {
                    uint4 ix = *(const uint4*)&rw[e];
                    uint4 v0 = gin[(size_t)ix.x * 8 + c];
                    uint4 v1 = gin[(size_t)ix.y * 8 + c];
                    uint4 v2 = gin[(size_t)ix.z * 8 + c];
                    uint4 v3 = gin[(size_t)ix.w * 8 + c];
                    ACCX(v0) ACCX(v1) ACCX(v2) ACCX(v3)
                }
                for (; e < cnt; ++e) {
                    uint4 v = gin[(size_t)rw[e] * 8 + c];
                    ACCX(v)
                }
            }
            uint4 pk;
            pk.x = bpack(a0, a1); pk.y = bpack(a2, a3);
            pk.z = bpack(a4, a5); pk.w = bpack(a6, a7);
            *(uint4*)&sU[rr * 72 + c * 8] = pk;      // 16B aligned (144*rr + 16c)
        }
#undef ACCX
    }
    __syncthreads();

    // A-frags from LDS
    const int mrow = 16 * w + (l & 15);
    bf16x8 a1f = *(bf16x8*)&sU[mrow * 72 + (l >> 4) * 8];
    bf16x8 a2f = *(bf16x8*)&sU[mrow * 72 + 32 + (l >> 4) * 8];
    __syncthreads();                                 // sU reads done; reuse as sTb

    short* sTb = (short*)sMix;                       // [64][72] bf16
#pragma unroll
    for (int c = 0; c < 4; ++c) {
        f32x4 acc = {0.f, 0.f, 0.f, 0.f};
        uint4 b0u = wf4[(c * 2 + 0) * 64 + l];       // coalesced, L2-hit
        uint4 b1u = wf4[(c * 2 + 1) * 64 + l];
        acc = __builtin_amdgcn_mfma_f32_16x16x32_bf16(a1f, *(bf16x8*)&b0u, acc, 0, 0, 0);
        acc = __builtin_amdgcn_mfma_f32_16x16x32_bf16(a2f, *(bf16x8*)&b1u, acc, 0, 0, 0);
        int col = c * 16 + (l & 15);
        float bb = sb1[col];
#pragma unroll
        for (int r = 0; r < 4; ++r) {
            int m = 16 * w + (l >> 4) * 4 + r;
            sTb[m * 72 + col] = bf1(fmaxf(acc[r] + bb, 0.f));
        }
    }
    __syncthreads();
    bf16x8 ta1 = *(bf16x8*)&sTb[mrow * 72 + (l >> 4) * 8];
    bf16x8 ta2 = *(bf16x8*)&sTb[mrow * 72 + 32 + (l >> 4) * 8];
    __syncthreads();                                 // sTb reads done; alias as sOut
    float (*sOut)[68] = (float(*)[68])sMix;
#pragma unroll
    for (int c = 0; c < 4; ++c) {
        f32x4 acc = {0.f, 0.f, 0.f, 0.f};
        uint4 b0u = wf4[512 + (c * 2 + 0) * 64 + l];
        uint4 b1u = wf4[512 + (c * 2 + 1) * 64 + l];
        acc = __builtin_amdgcn_mfma_f32_16x16x32_bf16(ta1, *(bf16x8*)&b0u, acc, 0, 0, 0);
        acc = __builtin_amdgcn_mfma_f32_16x16x32_bf16(ta2, *(bf16x8*)&b1u, acc, 0, 0, 0);
        int col = c * 16 + (l & 15);
        float bb = sb2[col];
#pragma unroll
        for (int r = 0; r < 4; ++r)
            sOut[16 * w + (l >> 4) * 4 + r][col] = fmaxf(acc[r] + bb, 0.f);
    }
    __syncthreads();
    {
        int row = t >> 2, q = t & 3;
        int grow = base + row;
        if (grow < NN) {
            const float* sp = &sOut[row][q * 16];
            uint4 o1, o2;
            o1.x = bpack(sp[0], sp[1]);  o1.y = bpack(sp[2], sp[3]);
            o1.z = bpack(sp[4], sp[5]);  o1.w = bpack(sp[6], sp[7]);
            o2.x = bpack(sp[8], sp[9]);  o2.y = bpack(sp[10], sp[11]);
            o2.z = bpack(sp[12], sp[13]); o2.w = bpack(sp[14], sp[15]);
            hout[(size_t)grow * 8 + 2 * q]     = o1;
            hout[(size_t)grow * 8 + 2 * q + 1] = o2;
        }
    }
    if (t < 64) {
        const int j = t;
        float pa = 0.f;
        int gprev = -1;
        for (int r = 0; r < 64; ++r) {
            int row = base + r;
            if (row >= NN) break;
            int g = sbatch[r];
            if (g != gprev) {
                if (gprev >= 0) atomicAdd(&p[gprev * 192 + layer * 64 + j], pa);
                pa = 0.f; gprev = g;
            }
            pa += sOut[r][j];
        }
        if (gprev >= 0) atomicAdd(&p[gprev * 192 + layer * 64 + j], pa);
    }
}

__global__ __launch_bounds__(192) void k_final(const float* __restrict__ p,
                                               const float* __restrict__ W1, const float* __restrict__ b1,
                                               const float* __restrict__ W2, const float* __restrict__ b2,
                                               float* __restrict__ out) {
    int g = blockIdx.x, t = threadIdx.x;
    __shared__ float hg[192];
    __shared__ float y1[192];
    __shared__ float y2[2];
    hg[t] = p[g * 192 + t];
    __syncthreads();
    float acc = b1[t];
    for (int k = 0; k < 192; ++k) acc = fmaf(hg[k], W1[k * 192 + t], acc);
    y1[t] = fmaxf(acc, 0.f);
    __syncthreads();
    if (t < 2) {
        float a = b2[t];
        for (int k = 0; k < 192; ++k) a = fmaf(y1[k], W2[k * 2 + t], a);
        y2[t] = a;
    }
    __syncthreads();
    if (t < 2) {
        float m = fmaxf(y2[0], y2[1]);
        float s = expf(y2[0] - m) + expf(y2[1] - m);
        out[g * 2 + t] = y2[t];
        out[NG * 2 + g * 2 + t] = expf(y2[t] - m) / s;
    }
}

extern "C" void kernel_launch(void* const* d_in, const int* in_sizes, int n_in,
                              void* d_out, int out_size, void* d_ws, size_t ws_size,
                              hipStream_t stream) {
    const float* x    = (const float*)d_in[0];
    const int* ei     = (const int*)d_in[1];
    const int* batch  = (const int*)d_in[2];
    const int* src    = ei;
    const int* dst    = ei + NE;
    const float* lin1_W = (const float*)d_in[27];
    const float* lin1_b = (const float*)d_in[28];
    const float* lin2_W = (const float*)d_in[29];
    const float* lin2_b = (const float*)d_in[30];

    // ws layout (max offset 67,993,216 <= 71,193,216 proven available):
    char* w = (char*)d_ws;
    int*      deg   = (int*)w;                               //   400,000
    float*    p     = (float*)(w + 400000);                  //   393,216
    unsigned* bins2 = (unsigned*)(w + 793216);               //  9,633,792
    int*      bcnt2 = (int*)(w + 10427008);                  //    100,352
    unsigned* wf3   = (unsigned*)(w + 13600000);             //     49,152
    float*    bias3 = (float*)(w + 13649152);                //      1,536
    unsigned* bins  = (unsigned*)(w + 13700000);             //  8,388,608
    int*      bcnt  = (int*)(w + 22100000);                  //     32,768
    char*     xbhB  = w + 26393216;                          // 12,800,000 bf16: x_bf, later hB
    char*     hA    = w + 39193216;                          // 12,800,000 bf16
    int*      csr40 = (int*)(w + 51993216);                  // 16,000,000 [NN][NCAP]

    k_zero_int<<<(NG * 192 + 255) / 256, 256, 0, stream>>>((int*)p, NG * 192);
    k_cvt<<<(NN * 8 + 255) / 256, 256, 0, stream>>>((const float4*)x, (uint4*)xbhB, NN * 8);
    WP3 wp;
    for (int l = 0; l < 3; ++l) {
        wp.l[l].W1 = (const float*)d_in[3 + 8 * l + 0];
        wp.l[l].b1 = (const float*)d_in[3 + 8 * l + 1];
        wp.l[l].ga = (const float*)d_in[3 + 8 * l + 2];
        wp.l[l].be = (const float*)d_in[3 + 8 * l + 3];
        wp.l[l].rm = (const float*)d_in[3 + 8 * l + 4];
        wp.l[l].rv = (const float*)d_in[3 + 8 * l + 5];
        wp.l[l].W2 = (const float*)d_in[3 + 8 * l + 6];
        wp.l[l].b2 = (const float*)d_in[3 + 8 * l + 7];
    }
    k_wprep3<<<3, 256, 0, stream>>>(wp, wf3, bias3);
    // 3-pass CSR build: no global atomics, sequential global writes only
    k_binA<<<ABLK, 256, 0, stream>>>(src, dst, bins, bcnt);
    k_binB2<<<8 * BBLK, 256, 0, stream>>>(bins, bcnt, bins2, bcnt2);
    k_binC<<<8 * NSUB, 256, 0, stream>>>(bins2, bcnt2, deg, csr40);

    const uint4* gin[3]  = { (const uint4*)xbhB, (const uint4*)hA, (const uint4*)xbhB };
    uint4*       gout[3] = { (uint4*)hA,         (uint4*)xbhB,     (uint4*)hA };
    for (int l = 0; l < 3; ++l) {
        k_layer<<<(NN + 63) / 64, 256, 0, stream>>>(gin[l], gout[l], deg, csr40, batch, p, l,
                                                    (const uint4*)(wf3 + l * 4096), bias3 + l * 128);
    }
    k_final<<<NG, 192, 0, stream>>>(p, lin1_W, lin1_b, lin2_W, lin2_b, (float*)d_out);
}

// Round 16
// 173.125 us; speedup vs baseline: 1.9976x; 1.0585x over previous
//
#include <hip/hip_runtime.h>

#define NN 100000
#define NE 1200000
#define HD 64
#define NG 512
#define BN_EPS 1e-5f
#define SLICE 12500     // NN/8 dst-nodes per shard
#define ABLK 1024       // pass-A blocks
#define ACHUNK 1172     // ceil(NE/ABLK)
#define BINCAP 256      // per-(Ablock,shard) capacity; mean 146.5, +9 sigma
#define BBLK 32         // pass-B blocks per shard (256 total)
#define NSUB 98         // 128-node sub-bins per shard
#define SUBCAP 96       // per-(Bblock,sub) capacity; mean 47.8, +7 sigma
#define NCAP 40         // per-node list cap; P(Poisson(12)>=40) ~ 1e-10
#define CVTB 512        // cvt blocks inside k_prep

typedef short bf16x8 __attribute__((ext_vector_type(8)));
typedef float f32x4  __attribute__((ext_vector_type(4)));

__device__ __forceinline__ float bf_lo(unsigned v) { return __uint_as_float(v << 16); }
__device__ __forceinline__ float bf_hi(unsigned v) { return __uint_as_float(v & 0xffff0000u); }
__device__ __forceinline__ unsigned bpack(float a, float b) {
    unsigned ua = __float_as_uint(a), ub = __float_as_uint(b);
    ua = (ua + 0x7fffu + ((ua >> 16) & 1u)) >> 16;
    ub = (ub + 0x7fffu + ((ub >> 16) & 1u)) >> 16;
    return ua | (ub << 16);
}
__device__ __forceinline__ short bf1(float a) {
    unsigned ua = __float_as_uint(a);
    return (short)((ua + 0x7fffu + ((ua >> 16) & 1u)) >> 16);
}

struct WP { const float *W1, *b1, *ga, *be, *rm, *rv, *W2, *b2; };
struct WP3 { WP l[3]; };

// Fused prologue: [0,ABLK) = binA; [ABLK,ABLK+CVTB) = x->bf16 cvt;
// [+3) = per-layer weight prep; [+2) = zero p. All independent.
__global__ __launch_bounds__(256) void k_prep(const float4* __restrict__ xf, uint4* __restrict__ xb,
                                              const int* __restrict__ src, const int* __restrict__ dst,
                                              unsigned* __restrict__ bins, int* __restrict__ bcnt,
                                              WP3 wp, unsigned* __restrict__ wf3, float* __restrict__ bias3,
                                              float* __restrict__ p) {
    const int B = blockIdx.x, t = threadIdx.x;
    if (B < ABLK) {
        // ---- binA: private LDS binning by shard, sequential segment writes ----
        __shared__ unsigned sb[8][BINCAP];
        __shared__ int scnt[8];
        if (t < 8) scnt[t] = 0;
        __syncthreads();
        const int e0 = B * ACHUNK;
        int e1 = e0 + ACHUNK; if (e1 > NE) e1 = NE;
        for (int e = e0 + t; e < e1; e += 256) {
            int d = dst[e], s = src[e];
            int g = d / SLICE;
            int pos = atomicAdd(&scnt[g], 1);
            if (pos < BINCAP) sb[g][pos] = ((unsigned)(d - g * SLICE) << 17) | (unsigned)s;
        }
        __syncthreads();
        for (int i = t; i < 8 * BINCAP; i += 256) {
            int g = i >> 8, pos = i & (BINCAP - 1);
            int c = scnt[g]; if (c > BINCAP) c = BINCAP;
            if (pos < c) bins[((size_t)B * 8 + g) * BINCAP + pos] = sb[g][pos];
        }
        if (t < 8) {
            int c = scnt[t]; if (c > BINCAP) c = BINCAP;
            bcnt[B * 8 + t] = c;
        }
    } else if (B < ABLK + CVTB) {
        // ---- cvt: fp32 -> packed bf16, grid-stride ----
        for (int i = (B - ABLK) * 256 + t; i < NN * 8; i += CVTB * 256) {
            float4 f0 = xf[2 * i], f1 = xf[2 * i + 1];
            uint4 o;
            o.x = bpack(f0.x, f0.y); o.y = bpack(f0.z, f0.w);
            o.z = bpack(f1.x, f1.y); o.w = bpack(f1.z, f1.w);
            xb[i] = o;
        }
    } else if (B < ABLK + CVTB + 3) {
        // ---- weight prep for layer L ----
        const int L = B - (ABLK + CVTB);
        const WP w = wp.l[L];
        unsigned* wf = wf3 + L * 4096;
        float* bias = bias3 + L * 128;
        __shared__ float ssc[64];
        if (t < 64) {
            float sc = w.ga[t] * rsqrtf(w.rv[t] + BN_EPS);
            ssc[t] = sc;
            bias[t] = (w.b1[t] - w.rm[t]) * sc + w.be[t];
            bias[64 + t] = w.b2[t];
        }
        __syncthreads();
        for (int i = 0; i < 16; ++i) {
            int idx = t + 256 * i;
            int wpi = idx & 3;
            int l  = (idx >> 2) & 63;
            int th = (idx >> 8) & 7;
            int g  = idx >> 11;
            int h  = th & 1;
            int col = (th >> 1) * 16 + (l & 15);
            int k0 = h * 32 + (l >> 4) * 8 + 2 * wpi;
            float w0, w1;
            if (g == 0) { w0 = w.W1[k0 * 64 + col] * ssc[col]; w1 = w.W1[(k0 + 1) * 64 + col] * ssc[col]; }
            else        { w0 = w.W2[k0 * 64 + col];            w1 = w.W2[(k0 + 1) * 64 + col]; }
            wf[idx] = bpack(w0, w1);
        }
    } else {
        // ---- zero p ----
        int* pi = (int*)p;
        for (int i = (B - (ABLK + CVTB + 3)) * 256 + t; i < NG * 192; i += 2 * 256)
            pi[i] = 0;
    }
}

// Pass B: 32 blocks per shard re-bin into 98 sub-bins of 128 nodes.
__global__ __launch_bounds__(256) void k_binB2(const unsigned* __restrict__ bins, const int* __restrict__ bcnt,
                                               unsigned* __restrict__ bins2, int* __restrict__ bcnt2) {
    __shared__ int cur[NSUB];
    const int g = blockIdx.x / BBLK;
    const int j = blockIdx.x % BBLK;
    const int t = threadIdx.x;
    for (int i = t; i < NSUB; i += 256) cur[i] = 0;
    __syncthreads();
    const size_t obase = ((size_t)(g * BBLK + j) * NSUB) * SUBCAP;
    for (int b = j; b < ABLK; b += BBLK) {
        int c = bcnt[b * 8 + g];
        const unsigned* seg = bins + ((size_t)b * 8 + g) * BINCAP;
        for (int i = t; i < c; i += 256) {
            unsigned v = seg[i];
            int dl = (int)(v >> 17);
            int sub = dl >> 7;
            int pos = atomicAdd(&cur[sub], 1);
            if (pos < SUBCAP)
                bins2[obase + (size_t)sub * SUBCAP + pos] = ((unsigned)(dl & 127) << 17) | (v & 0x1FFFFu);
        }
    }
    __syncthreads();
    for (int i = t; i < NSUB; i += 256) {
        int c = cur[i]; if (c > SUBCAP) c = SUBCAP;
        bcnt2[(g * BBLK + j) * NSUB + i] = c;
    }
}

// Pass C: one block per 128-node sub-bin; per-node lists in LDS, coalesced writes.
__global__ __launch_bounds__(256) void k_binC(const unsigned* __restrict__ bins2, const int* __restrict__ bcnt2,
                                              int* __restrict__ deg, int* __restrict__ csr40) {
    __shared__ int lists[128 * NCAP];
    __shared__ int cur[128];
    __shared__ int jc[BBLK];
    const int g = blockIdx.x / NSUB;
    const int sub = blockIdx.x % NSUB;
    const int t = threadIdx.x;
    if (t < 128) cur[t] = 0;
    if (t < BBLK) jc[t] = bcnt2[(g * BBLK + t) * NSUB + sub];
    __syncthreads();
    for (int j = 0; j < BBLK; ++j) {
        int c = jc[j];
        const unsigned* seg = bins2 + ((size_t)(g * BBLK + j) * NSUB + sub) * SUBCAP;
        for (int i = t; i < c; i += 256) {
            unsigned v = seg[i];
            int d7 = (int)(v >> 17);
            int pos = atomicAdd(&cur[d7], 1);
            if (pos < NCAP) lists[d7 * NCAP + pos] = (int)(v & 0x1FFFFu);
        }
    }
    __syncthreads();
    const int node_base = g * SLICE + sub * 128;
    int nlim = SLICE - sub * 128; if (nlim > 128) nlim = 128;
    for (int i = t; i < nlim * NCAP; i += 256) csr40[(size_t)node_base * NCAP + i] = lists[i];
    for (int i = t; i < nlim; i += 256) {
        int c = cur[i]; if (c > NCAP) c = NCAP;
        deg[node_base + i] = c;
    }
}

// Fused layer: coalesced gather into LDS (8 lanes/node) + MFMA MLP (B-frags
// from L2-resident global wf) + bf16 h write + pool. LDS ~18 KB, 8 blocks/CU.
__global__ __launch_bounds__(256) void k_layer(const uint4* __restrict__ gin, uint4* __restrict__ hout,
                                               const int* __restrict__ deg, const int* __restrict__ csr40,
                                               const int* __restrict__ batch, float* __restrict__ p, int layer,
                                               const uint4* __restrict__ wf4, const float* __restrict__ bias) {
    __shared__ __align__(16) char sMix[64 * 68 * 4]; // sU bf16 -> sTb bf16 -> sOut fp32
    __shared__ float sb1[64], sb2[64];
    __shared__ int sbatch[64];
    const int t = threadIdx.x;
    const int base = blockIdx.x * 64;
    const int w = t >> 6, l = t & 63;

    if (t < 64) {
        sb1[t] = bias[t];
        sb2[t] = bias[64 + t];
        int row = base + t;
        sbatch[t] = (row < NN) ? batch[row] : -1;
    }

    short* sU = (short*)sMix;                        // [64][72] bf16
    {
        const int grp = t >> 3;
        const int c = t & 7;
#define ACCX(vv) { a0 += bf_lo(vv.x); a1 += bf_hi(vv.x); a2 += bf_lo(vv.y); a3 += bf_hi(vv.y); \
                   a4 += bf_lo(vv.z); a5 += bf_hi(vv.z); a6 += bf_lo(vv.w); a7 += bf_hi(vv.w); }
        for (int rr = grp; rr < 64; rr += 32) {
            int row = base + rr;
            float a0 = 0.f, a1 = 0.f, a2 = 0.f, a3 = 0.f, a4 = 0.f, a5 = 0.f, a6 = 0.f, a7 = 0.f;
            if (row < NN) {
                uint4 sv = gin[(size_t)row * 8 + c];
                ACCX(sv)
                int cnt = deg[row]; if (cnt > NCAP) cnt = NCAP;
                const int* rw = csr40 + (size_t)row * NCAP;
                int e = 0;
                for (; e + 4 <= cnt; e += 4) {
                    uint4 ix = *(const uint4*)&rw[e];
                    uint4 v0 = gin[(size_t)ix.x * 8 + c];
                    uint4 v1 = gin[(size_t)ix.y * 8 + c];
                    uint4 v2 = gin[(size_t)ix.z * 8 + c];
                    uint4 v3 = gin[(size_t)ix.w * 8 + c];
                    ACCX(v0) ACCX(v1) ACCX(v2) ACCX(v3)
                }
                for (; e < cnt; ++e) {
                    uint4 v = gin[(size_t)rw[e] * 8 + c];
                    ACCX(v)
                }
            }
            uint4 pk;
            pk.x = bpack(a0, a1); pk.y = bpack(a2, a3);
            pk.z = bpack(a4, a5); pk.w = bpack(a6, a7);
            *(uint4*)&sU[rr * 72 + c * 8] = pk;
        }
#undef ACCX
    }
    __syncthreads();

    const int mrow = 16 * w + (l & 15);
    bf16x8 a1f = *(bf16x8*)&sU[mrow * 72 + (l >> 4) * 8];
    bf16x8 a2f = *(bf16x8*)&sU[mrow * 72 + 32 + (l >> 4) * 8];
    __syncthreads();

    short* sTb = (short*)sMix;
#pragma unroll
    for (int c = 0; c < 4; ++c) {
        f32x4 acc = {0.f, 0.f, 0.f, 0.f};
        uint4 b0u = wf4[(c * 2 + 0) * 64 + l];
        uint4 b1u = wf4[(c * 2 + 1) * 64 + l];
        acc = __builtin_amdgcn_mfma_f32_16x16x32_bf16(a1f, *(bf16x8*)&b0u, acc, 0, 0, 0);
        acc = __builtin_amdgcn_mfma_f32_16x16x32_bf16(a2f, *(bf16x8*)&b1u, acc, 0, 0, 0);
        int col = c * 16 + (l & 15);
        float bb = sb1[col];
#pragma unroll
        for (int r = 0; r < 4; ++r) {
            int m = 16 * w + (l >> 4) * 4 + r;
            sTb[m * 72 + col] = bf1(fmaxf(acc[r] + bb, 0.f));
        }
    }
    __syncthreads();
    bf16x8 ta1 = *(bf16x8*)&sTb[mrow * 72 + (l >> 4) * 8];
    bf16x8 ta2 = *(bf16x8*)&sTb[mrow * 72 + 32 + (l >> 4) * 8];
    __syncthreads();
    float (*sOut)[68] = (float(*)[68])sMix;
#pragma unroll
    for (int c = 0; c < 4; ++c) {
        f32x4 acc = {0.f, 0.f, 0.f, 0.f};
        uint4 b0u = wf4[512 + (c * 2 + 0) * 64 + l];
        uint4 b1u = wf4[512 + (c * 2 + 1) * 64 + l];
        acc = __builtin_amdgcn_mfma_f32_16x16x32_bf16(ta1, *(bf16x8*)&b0u, acc, 0, 0, 0);
        acc = __builtin_amdgcn_mfma_f32_16x16x32_bf16(ta2, *(bf16x8*)&b1u, acc, 0, 0, 0);
        int col = c * 16 + (l & 15);
        float bb = sb2[col];
#pragma unroll
        for (int r = 0; r < 4; ++r)
            sOut[16 * w + (l >> 4) * 4 + r][col] = fmaxf(acc[r] + bb, 0.f);
    }
    __syncthreads();
    {
        int row = t >> 2, q = t & 3;
        int grow = base + row;
        if (grow < NN) {
            const float* sp = &sOut[row][q * 16];
            uint4 o1, o2;
            o1.x = bpack(sp[0], sp[1]);  o1.y = bpack(sp[2], sp[3]);
            o1.z = bpack(sp[4], sp[5]);  o1.w = bpack(sp[6], sp[7]);
            o2.x = bpack(sp[8], sp[9]);  o2.y = bpack(sp[10], sp[11]);
            o2.z = bpack(sp[12], sp[13]); o2.w = bpack(sp[14], sp[15]);
            hout[(size_t)grow * 8 + 2 * q]     = o1;
            hout[(size_t)grow * 8 + 2 * q + 1] = o2;
        }
    }
    if (t < 64) {
        const int j = t;
        float pa = 0.f;
        int gprev = -1;
        for (int r = 0; r < 64; ++r) {
            int row = base + r;
            if (row >= NN) break;
            int g = sbatch[r];
            if (g != gprev) {
                if (gprev >= 0) atomicAdd(&p[gprev * 192 + layer * 64 + j], pa);
                pa = 0.f; gprev = g;
            }
            pa += sOut[r][j];
        }
        if (gprev >= 0) atomicAdd(&p[gprev * 192 + layer * 64 + j], pa);
    }
}

// Final head, 4 graphs per block: W1 loads reused x4.
__global__ __launch_bounds__(192) void k_final4(const float* __restrict__ p,
                                                const float* __restrict__ W1, const float* __restrict__ b1,
                                                const float* __restrict__ W2, const float* __restrict__ b2,
                                                float* __restrict__ out) {
    int g0 = blockIdx.x * 4, t = threadIdx.x;
    __shared__ float hg[4][192];
    __shared__ float y1[4][192];
    __shared__ float y2[4][2];
#pragma unroll
    for (int q = 0; q < 4; ++q) hg[q][t] = p[(g0 + q) * 192 + t];
    __syncthreads();
    float b = b1[t];
    float acc0 = b, acc1 = b, acc2 = b, acc3 = b;
    for (int k = 0; k < 192; ++k) {
        float wv = W1[k * 192 + t];
        acc0 = fmaf(hg[0][k], wv, acc0);
        acc1 = fmaf(hg[1][k], wv, acc1);
        acc2 = fmaf(hg[2][k], wv, acc2);
        acc3 = fmaf(hg[3][k], wv, acc3);
    }
    y1[0][t] = fmaxf(acc0, 0.f); y1[1][t] = fmaxf(acc1, 0.f);
    y1[2][t] = fmaxf(acc2, 0.f); y1[3][t] = fmaxf(acc3, 0.f);
    __syncthreads();
    if (t < 8) {
        int q = t >> 1, col = t & 1;
        float a = b2[col];
        for (int k = 0; k < 192; ++k) a = fmaf(y1[q][k], W2[k * 2 + col], a);
        y2[q][col] = a;
    }
    __syncthreads();
    if (t < 8) {
        int q = t >> 1, col = t & 1;
        int g = g0 + q;
        float m = fmaxf(y2[q][0], y2[q][1]);
        float s = expf(y2[q][0] - m) + expf(y2[q][1] - m);
        out[g * 2 + col] = y2[q][col];
        out[NG * 2 + g * 2 + col] = expf(y2[q][col] - m) / s;
    }
}

extern "C" void kernel_launch(void* const* d_in, const int* in_sizes, int n_in,
                              void* d_out, int out_size, void* d_ws, size_t ws_size,
                              hipStream_t stream) {
    const float* x    = (const float*)d_in[0];
    const int* ei     = (const int*)d_in[1];
    const int* batch  = (const int*)d_in[2];
    const int* src    = ei;
    const int* dst    = ei + NE;
    const float* lin1_W = (const float*)d_in[27];
    const float* lin1_b = (const float*)d_in[28];
    const float* lin2_W = (const float*)d_in[29];
    const float* lin2_b = (const float*)d_in[30];

    // ws layout (max offset 67,993,216 <= 71,193,216 proven available):
    char* w = (char*)d_ws;
    int*      deg   = (int*)w;                               //   400,000
    float*    p     = (float*)(w + 400000);                  //   393,216
    unsigned* bins2 = (unsigned*)(w + 793216);               //  9,633,792
    int*      bcnt2 = (int*)(w + 10427008);                  //    100,352
    unsigned* wf3   = (unsigned*)(w + 13600000);             //     49,152
    float*    bias3 = (float*)(w + 13649152);                //      1,536
    unsigned* bins  = (unsigned*)(w + 13700000);             //  8,388,608
    int*      bcnt  = (int*)(w + 22100000);                  //     32,768
    char*     xbhB  = w + 26393216;                          // 12,800,000 bf16: x_bf, later hB
    char*     hA    = w + 39193216;                          // 12,800,000 bf16
    int*      csr40 = (int*)(w + 51993216);                  // 16,000,000 [NN][NCAP]

    WP3 wp;
    for (int l = 0; l < 3; ++l) {
        wp.l[l].W1 = (const float*)d_in[3 + 8 * l + 0];
        wp.l[l].b1 = (const float*)d_in[3 + 8 * l + 1];
        wp.l[l].ga = (const float*)d_in[3 + 8 * l + 2];
        wp.l[l].be = (const float*)d_in[3 + 8 * l + 3];
        wp.l[l].rm = (const float*)d_in[3 + 8 * l + 4];
        wp.l[l].rv = (const float*)d_in[3 + 8 * l + 5];
        wp.l[l].W2 = (const float*)d_in[3 + 8 * l + 6];
        wp.l[l].b2 = (const float*)d_in[3 + 8 * l + 7];
    }

    // fused prologue: binA + cvt + wprep3 + zero-p in one launch
    k_prep<<<ABLK + CVTB + 3 + 2, 256, 0, stream>>>((const float4*)x, (uint4*)xbhB,
                                                    src, dst, bins, bcnt, wp, wf3, bias3, p);
    k_binB2<<<8 * BBLK, 256, 0, stream>>>(bins, bcnt, bins2, bcnt2);
    k_binC<<<8 * NSUB, 256, 0, stream>>>(bins2, bcnt2, deg, csr40);

    const uint4* gin[3]  = { (const uint4*)xbhB, (const uint4*)hA, (const uint4*)xbhB };
    uint4*       gout[3] = { (uint4*)hA,         (uint4*)xbhB,     (uint4*)hA };
    for (int l = 0; l < 3; ++l) {
        k_layer<<<(NN + 63) / 64, 256, 0, stream>>>(gin[l], gout[l], deg, csr40, batch, p, l,
                                                    (const uint4*)(wf3 + l * 4096), bias3 + l * 128);
    }
    k_final4<<<NG / 4, 192, 0, stream>>>(p, lin1_W, lin1_b, lin2_W, lin2_b, (float*)d_out);
}